// Round 2
// baseline (289.768 us; speedup 1.0000x reference)
//
#include <hip/hip_runtime.h>

// Problem: B=8, C=256, N=2048, fp32.
// attn_b = (M_b Wk / S) x_b + (M_b bk / S) 1^T
//   M_b = Wv G_b Wq^T + wvsx_b bq^T + bv tq_b^T
//   G_b = x_b x_b^T (symmetric),  sx_b = rowsum_n(x_b)
//   S   = sum_b (Wq sx_b + N bq) . (Wk sx_b + N bk)

// ---------------- rowsum over n: sx[b*C+c] = sum_n x[b,c,n] ----------------
__launch_bounds__(256)
__global__ void rowsum_kernel(const float* __restrict__ x, float* __restrict__ sx) {
    const int row = blockIdx.x;                 // 0..B*C-1
    const float* xr = x + (long)row * 2048;
    const int t = threadIdx.x;
    float s = 0.0f;
    #pragma unroll
    for (int i = 0; i < 8; ++i) s += xr[t + 256 * i];   // coalesced
    __shared__ float red[256];
    red[t] = s; __syncthreads();
    for (int h = 128; h > 0; h >>= 1) {
        if (t < h) red[t] += red[t + h];
        __syncthreads();
    }
    if (t == 0) sx[row] = red[0];
}

// ---- per-batch stats ----
__launch_bounds__(256)
__global__ void stats_kernel(const float* __restrict__ Wq, const float* __restrict__ bq,
                             const float* __restrict__ Wk, const float* __restrict__ bk,
                             const float* __restrict__ Wv, const float* __restrict__ sx,
                             float* __restrict__ wqsx, float* __restrict__ tq,
                             float* __restrict__ wvsx, float* __restrict__ Sacc) {
    const int b = blockIdx.x;
    const int o = threadIdx.x;
    __shared__ float ssx[256];
    ssx[o] = sx[b * 256 + o];
    __syncthreads();
    float aq = 0.0f, ak = 0.0f, av = 0.0f;
    #pragma unroll 4
    for (int c = 0; c < 256; ++c) {
        const float s = ssx[c];
        aq = fmaf(Wq[o * 256 + c], s, aq);
        ak = fmaf(Wk[o * 256 + c], s, ak);
        av = fmaf(Wv[o * 256 + c], s, av);
    }
    wqsx[b * 256 + o] = aq;
    wvsx[b * 256 + o] = av;
    const float tqo = aq + 2048.0f * bq[o];
    const float tko = ak + 2048.0f * bk[o];
    tq[b * 256 + o] = tqo;
    __shared__ float red[256];
    red[o] = tqo * tko; __syncthreads();
    for (int h = 128; h > 0; h >>= 1) {
        if (o < h) red[o] += red[o + h];
        __syncthreads();
    }
    if (o == 0) atomicAdd(Sacc, red[0]);
}

// ---- c_b[o] = (1/S) * sum_c M_b[o,c] bk[c] ----
__launch_bounds__(256)
__global__ void cvec_kernel(const float* __restrict__ M, const float* __restrict__ bk,
                            const float* __restrict__ Sptr, float* __restrict__ cvec) {
    const int b = blockIdx.x;
    const int o = threadIdx.x;
    const float* Mr = M + (long)b * 65536 + (long)o * 256;
    float s = 0.0f;
    #pragma unroll 4
    for (int c = 0; c < 256; ++c) s = fmaf(Mr[c], bk[c], s);
    cvec[b * 256 + o] = s / Sptr[0];
}

// ---- mirror lower-left 128x128 of symmetric G from upper-right ----
// grid (4,4,8), block (32,8)
__global__ void mirror_kernel(float* __restrict__ G) {
    __shared__ float tile[32][33];
    const int b = blockIdx.z;
    const int c0 = blockIdx.x * 32;          // 0..96
    const int r0 = 128 + blockIdx.y * 32;    // 128..224
    float* Gb = G + (long)b * 65536;
    const int tx = threadIdx.x, ty = threadIdx.y;
    #pragma unroll
    for (int i = ty; i < 32; i += 8)
        tile[i][tx] = Gb[(c0 + i) * 256 + r0 + tx];   // coalesced read
    __syncthreads();
    #pragma unroll
    for (int i = ty; i < 32; i += 8)
        Gb[(r0 + i) * 256 + c0 + tx] = tile[tx][i];   // coalesced write
}

// ---------------- tiled fp32 GEMM: D = A @ B (+ epilogue) ----------------
// Tile BM x 64, BK=16, 256 threads, TM x 4 per thread.
// LDS pitches padded: PA=BM+4, PB=68 -> staging/store conflicts collapse to
// free 2-way (m136). A row-major [rows][K]; TRANSB: B[j][k]=Bmat[j*ldb+k].
// EPI: 0 store; 1 +e1[b,r]*e2[col]+e3[r]*e4[b,col]; 2 *(1/S); 3 +e1[b,r]; 4 atomicAdd.
template <int BM, int TM, bool TRANSB, int EPI, bool SYMSKIP>
__launch_bounds__(256)
__global__ void gemm(const float* __restrict__ Amat, long aBatch, int lda,
                     const float* __restrict__ Bmat, long bBatch, int ldb,
                     float* __restrict__ Dmat, long dBatch, int ldd,
                     int K, int kSplit,
                     const float* __restrict__ e1, const float* __restrict__ e2,
                     const float* __restrict__ e3, const float* __restrict__ e4,
                     const float* __restrict__ Sptr) {
    constexpr int PA = BM + 4;
    constexpr int PB = 68;
    __shared__ float ldsA[16 * PA];
    __shared__ float ldsB[16 * PB];

    const int r0 = blockIdx.y * BM;
    const int j0 = blockIdx.x * 64;
    if (SYMSKIP && r0 >= j0 + 64) return;   // tile entirely below diagonal

    const int b  = blockIdx.z / kSplit;
    const int ks = blockIdx.z % kSplit;
    const int kLen = K / kSplit;
    int kk = ks * kLen;
    const int kEnd = kk + kLen;

    const float* A = Amat + (long)b * aBatch;
    const float* B = Bmat + (long)b * bBatch;
    float* D = Dmat + (long)b * dBatch;

    const int t  = threadIdx.x;
    const int tx = t & 15, ty = t >> 4;
    const int sr = t >> 2;            // 0..63
    const int sk = (t & 3) * 4;       // 0,4,8,12

    float acc[TM][4] = {};

    for (; kk < kEnd; kk += 16) {
        #pragma unroll
        for (int p = 0; p < BM / 64; ++p) {
            const float4 a4 = *(const float4*)&A[(long)(r0 + p * 64 + sr) * lda + kk + sk];
            ldsA[(sk + 0) * PA + p * 64 + sr] = a4.x;
            ldsA[(sk + 1) * PA + p * 64 + sr] = a4.y;
            ldsA[(sk + 2) * PA + p * 64 + sr] = a4.z;
            ldsA[(sk + 3) * PA + p * 64 + sr] = a4.w;
        }
        if (TRANSB) {
            const float4 b4 = *(const float4*)&B[(long)(j0 + sr) * ldb + kk + sk];
            ldsB[(sk + 0) * PB + sr] = b4.x;
            ldsB[(sk + 1) * PB + sr] = b4.y;
            ldsB[(sk + 2) * PB + sr] = b4.z;
            ldsB[(sk + 3) * PB + sr] = b4.w;
        } else {
            const float4 b4 = *(const float4*)&B[(long)(kk + ty) * ldb + j0 + tx * 4];
            *(float4*)&ldsB[ty * PB + tx * 4] = b4;
        }
        __syncthreads();
        #pragma unroll
        for (int k = 0; k < 16; ++k) {
            float a[TM];
            *(float4*)&a[0] = *(const float4*)&ldsA[k * PA + ty * TM];
            if constexpr (TM == 8)
                *(float4*)&a[4] = *(const float4*)&ldsA[k * PA + ty * TM + 4];
            const float4 bb = *(const float4*)&ldsB[k * PB + tx * 4];
            const float br[4] = {bb.x, bb.y, bb.z, bb.w};
            #pragma unroll
            for (int i = 0; i < TM; ++i)
                #pragma unroll
                for (int j = 0; j < 4; ++j)
                    acc[i][j] = fmaf(a[i], br[j], acc[i][j]);
        }
        __syncthreads();
    }

    const float invS = (EPI == 2) ? (1.0f / Sptr[0]) : 1.0f;
    #pragma unroll
    for (int i = 0; i < TM; ++i) {
        const int r = r0 + ty * TM + i;
        if (EPI == 4) {
            #pragma unroll
            for (int j = 0; j < 4; ++j)
                atomicAdd(&D[(long)r * ldd + j0 + tx * 4 + j], acc[i][j]);
        } else {
            float v[4];
            #pragma unroll
            for (int j = 0; j < 4; ++j) {
                const int col = j0 + tx * 4 + j;
                float val = acc[i][j];
                if (EPI == 1) val += e1[(long)b * 256 + r] * e2[col] + e3[r] * e4[(long)b * 256 + col];
                if (EPI == 2) val *= invS;
                if (EPI == 3) val += e1[(long)b * 256 + r];
                v[j] = val;
            }
            *(float4*)&D[(long)r * ldd + j0 + tx * 4] = make_float4(v[0], v[1], v[2], v[3]);
        }
    }
}

extern "C" void kernel_launch(void* const* d_in, const int* in_sizes, int n_in,
                              void* d_out, int out_size, void* d_ws, size_t ws_size,
                              hipStream_t stream) {
    const float* x  = (const float*)d_in[0];
    const float* Wq = (const float*)d_in[1];
    const float* bq = (const float*)d_in[2];
    const float* Wk = (const float*)d_in[3];
    const float* bk = (const float*)d_in[4];
    const float* Wv = (const float*)d_in[5];
    const float* bv = (const float*)d_in[6];
    float* out = (float*)d_out;
    float* ws  = (float*)d_ws;

    const int B = 8, C = 256, N = 2048;
    float* G    = ws;                 // [B,C,C], reused as Asc later
    float* T1   = ws + 524288;        // [B,C,C]
    float* M    = ws + 1048576;       // [B,C,C]
    float* sx   = ws + 1572864;       // [B,C]
    float* wqsx = ws + 1574912;       // [B,C]
    float* tq   = ws + 1576960;       // [B,C]
    float* wvsx = ws + 1579008;       // [B,C]
    float* cvec = ws + 1581056;       // [B,C]
    float* S    = ws + 1583104;       // [1]
    float* Asc  = G;

    hipMemsetAsync(G, 0, (size_t)B * C * C * sizeof(float), stream);
    hipMemsetAsync(S, 0, sizeof(float), stream);

    rowsum_kernel<<<dim3(B * C), 256, 0, stream>>>(x, sx);
    stats_kernel<<<dim3(B), 256, 0, stream>>>(Wq, bq, Wk, bk, Wv, sx, wqsx, tq, wvsx, S);

    // G_b = x_b x_b^T  (K=2048, splitK=8, symmetric tile skip, atomic combine)
    gemm<128, 8, true, 4, true><<<dim3(4, 2, B * 8), 256, 0, stream>>>(
        x, (long)C * N, N, x, (long)C * N, N, G, (long)C * C, C,
        N, 8, nullptr, nullptr, nullptr, nullptr, nullptr);

    // fill lower-left 128x128 of each G_b by transpose
    mirror_kernel<<<dim3(4, 4, B), dim3(32, 8), 0, stream>>>(G);

    // T1 = Wv @ G_b
    gemm<64, 4, false, 0, false><<<dim3(4, 4, B), 256, 0, stream>>>(
        Wv, 0, C, G, (long)C * C, C, T1, (long)C * C, C,
        C, 1, nullptr, nullptr, nullptr, nullptr, nullptr);

    // M_b = T1 @ Wq^T + wvsx_b (x) bq + bv (x) tq_b
    gemm<64, 4, true, 1, false><<<dim3(4, 4, B), 256, 0, stream>>>(
        T1, (long)C * C, C, Wq, 0, C, M, (long)C * C, C,
        C, 1, wvsx, bq, bv, tq, nullptr);

    // c_b = (M_b bk) / S
    cvec_kernel<<<dim3(B), 256, 0, stream>>>(M, bk, S, cvec);

    // Asc_b = (M_b @ Wk) / S
    gemm<64, 4, false, 2, false><<<dim3(4, 4, B), 256, 0, stream>>>(
        M, (long)C * C, C, Wk, 0, C, Asc, (long)C * C, C,
        C, 1, nullptr, nullptr, nullptr, nullptr, S);

    // out_b = Asc_b @ x_b + c_b
    gemm<128, 8, false, 3, false><<<dim3(N / 64, 2, B), 256, 0, stream>>>(
        Asc, (long)C * C, C, x, (long)C * N, N, out, (long)C * N, N,
        C, 1, cvec, nullptr, nullptr, nullptr, nullptr);
}

// Round 3
// 243.300 us; speedup vs baseline: 1.1910x; 1.1910x over previous
//
#include <hip/hip_runtime.h>

// B=8, C=256, N=2048, fp32 in/out.
// attn_b = (M_b Wk / S) x_b + (M_b bk / S) 1^T
//   M_b Wk = Wv G_b (Wq^T Wk) + wvsx_b (x) u2 + bv (x) v2_b,  W3 = Wq^T Wk
//   u2 = Wk^T bq, v2_b = Wk^T tq_b, tq_b = Wq sx_b + N bq
//   G_b = x_b x_b^T (symmetric), sx_b = rowsum(x_b)
//   M_b bk = T1_b w1 + wvsx_b (bq.bk) + bv (tq_b.bk),  w1 = Wq^T bk
//   S = sum_b tq_b . (Wk sx_b + N bk)
// Big GEMMs (G, final) use f16 hi/lo split MFMA (3 phases: hh, hl, lh).

typedef _Float16 half8 __attribute__((ext_vector_type(8)));
typedef _Float16 half4 __attribute__((ext_vector_type(4)));
typedef float f4v __attribute__((ext_vector_type(4)));

#define GP 40   // LDS pitch in halves for MFMA panels (16B-aligned rows, even bank spread)

// ---------------- rowsum: sx[b*C+c] = sum_n x[b,c,n] ----------------
__launch_bounds__(256)
__global__ void rowsum_kernel(const float* __restrict__ x, float* __restrict__ sx) {
    const int row = blockIdx.x;
    const float* xr = x + (long)row * 2048;
    const int t = threadIdx.x;
    float s = 0.0f;
    #pragma unroll
    for (int i = 0; i < 8; ++i) s += xr[t + 256 * i];
    __shared__ float red[256];
    red[t] = s; __syncthreads();
    for (int h = 128; h > 0; h >>= 1) { if (t < h) red[t] += red[t + h]; __syncthreads(); }
    if (t == 0) sx[row] = red[0];
}

// ---- per-batch stats: wqsx, wvsx, tq, S ----
__launch_bounds__(256)
__global__ void stats_kernel(const float* __restrict__ Wq, const float* __restrict__ bq,
                             const float* __restrict__ Wk, const float* __restrict__ bk,
                             const float* __restrict__ Wv, const float* __restrict__ sx,
                             float* __restrict__ wqsx, float* __restrict__ tq,
                             float* __restrict__ wvsx, float* __restrict__ Sacc) {
    const int b = blockIdx.x;
    const int o = threadIdx.x;
    __shared__ float ssx[256];
    ssx[o] = sx[b * 256 + o];
    __syncthreads();
    float aq = 0.0f, ak = 0.0f, av = 0.0f;
    #pragma unroll 4
    for (int c = 0; c < 256; ++c) {
        const float s = ssx[c];
        aq = fmaf(Wq[o * 256 + c], s, aq);
        ak = fmaf(Wk[o * 256 + c], s, ak);
        av = fmaf(Wv[o * 256 + c], s, av);
    }
    wqsx[b * 256 + o] = aq;
    wvsx[b * 256 + o] = av;
    const float tqo = aq + 2048.0f * bq[o];
    const float tko = ak + 2048.0f * bk[o];
    tq[b * 256 + o] = tqo;
    __shared__ float red[256];
    red[o] = tqo * tko; __syncthreads();
    for (int h = 128; h > 0; h >>= 1) { if (o < h) red[o] += red[o + h]; __syncthreads(); }
    if (o == 0) atomicAdd(Sacc, red[0]);
}

// ---- prep2: v2_b = Wk^T tq_b; u2 = Wk^T bq; w1 = Wq^T bk; s2_b = tq_b.bk; s1 = bq.bk ----
__launch_bounds__(256)
__global__ void prep2_kernel(const float* __restrict__ Wq, const float* __restrict__ Wk,
                             const float* __restrict__ bq, const float* __restrict__ bk,
                             const float* __restrict__ tq, float* __restrict__ v2,
                             float* __restrict__ u2, float* __restrict__ w1,
                             float* __restrict__ s2, float* __restrict__ s1) {
    const int b = blockIdx.x, j = threadIdx.x;
    __shared__ float stq[256], sbq[256], sbk[256];
    stq[j] = tq[b * 256 + j]; sbq[j] = bq[j]; sbk[j] = bk[j];
    __syncthreads();
    float a = 0.0f;
    #pragma unroll 4
    for (int c = 0; c < 256; ++c) a = fmaf(Wk[c * 256 + j], stq[c], a);
    v2[b * 256 + j] = a;
    if (b == 0) {
        float u = 0.0f, w = 0.0f;
        #pragma unroll 4
        for (int c = 0; c < 256; ++c) {
            u = fmaf(Wk[c * 256 + j], sbq[c], u);
            w = fmaf(Wq[c * 256 + j], sbk[c], w);
        }
        u2[j] = u; w1[j] = w;
    }
    __shared__ float red[256];
    red[j] = stq[j] * sbk[j]; __syncthreads();
    for (int h = 128; h > 0; h >>= 1) { if (j < h) red[j] += red[j + h]; __syncthreads(); }
    if (j == 0) s2[b] = red[0];
    if (b == 0) {
        __syncthreads();
        red[j] = sbq[j] * sbk[j]; __syncthreads();
        for (int h = 128; h > 0; h >>= 1) { if (j < h) red[j] += red[j + h]; __syncthreads(); }
        if (j == 0) s1[0] = red[0];
    }
}

// ---- cvec_b[o] = (T1_b[o,:].w1 + wvsx*s1 + bv*s2_b)/S ----
__launch_bounds__(256)
__global__ void cvec2_kernel(const float* __restrict__ T1, const float* __restrict__ w1,
                             const float* __restrict__ wvsx, const float* __restrict__ bv,
                             const float* __restrict__ s2, const float* __restrict__ s1,
                             const float* __restrict__ Sptr, float* __restrict__ cvec) {
    const int b = blockIdx.x, o = threadIdx.x;
    __shared__ float sw[256];
    sw[o] = w1[o]; __syncthreads();
    const float* r = T1 + (long)b * 65536 + (long)o * 256;
    float a = 0.0f;
    #pragma unroll 4
    for (int c = 0; c < 256; ++c) a = fmaf(r[c], sw[c], a);
    a += wvsx[b * 256 + o] * s1[0] + bv[o] * s2[b];
    cvec[b * 256 + o] = a / Sptr[0];
}

// ---- xT split: xTh/xTl[b][n][c] (f16) from x[b][c][n] (f32) ----
__global__ void xtsplit_kernel(const float* __restrict__ x, _Float16* __restrict__ xTh,
                               _Float16* __restrict__ xTl) {
    __shared__ float tile[32][33];
    const int b = blockIdx.z;
    const int n0 = blockIdx.x * 32, c0 = blockIdx.y * 32;
    const int tx = threadIdx.x, ty = threadIdx.y;
    const float* xb = x + (long)b * 524288;
    #pragma unroll
    for (int i = ty; i < 32; i += 8) tile[i][tx] = xb[(long)(c0 + i) * 2048 + n0 + tx];
    __syncthreads();
    #pragma unroll
    for (int i = ty; i < 32; i += 8) {
        const float v = tile[tx][i];
        const _Float16 h = (_Float16)v;
        const _Float16 l = (_Float16)(v - (float)h);
        const long o = (long)b * 524288 + (long)(n0 + i) * 256 + c0 + tx;
        xTh[o] = h; xTl[o] = l;
    }
}

// ---- mirror lower-left 128x128 of symmetric G from upper-right ----
__global__ void mirror_kernel(float* __restrict__ G) {
    __shared__ float tile[32][33];
    const int b = blockIdx.z;
    const int c0 = blockIdx.x * 32;
    const int r0 = 128 + blockIdx.y * 32;
    float* Gb = G + (long)b * 65536;
    const int tx = threadIdx.x, ty = threadIdx.y;
    #pragma unroll
    for (int i = ty; i < 32; i += 8) tile[i][tx] = Gb[(c0 + i) * 256 + r0 + tx];
    __syncthreads();
    #pragma unroll
    for (int i = ty; i < 32; i += 8) Gb[(r0 + i) * 256 + c0 + tx] = tile[tx][i];
}

// ---------------- G = x x^T via f16-split MFMA ----------------
// grid (2,2,B*8); tile 128x128; BK=32; splitK=8 -> Gpart[ks][b][tile]
__launch_bounds__(256)
__global__ void gemmG_mfma(const float* __restrict__ x, float* __restrict__ Gpart) {
    __shared__ __align__(16) _Float16 Ah[128 * GP];
    __shared__ __align__(16) _Float16 Al[128 * GP];
    __shared__ __align__(16) _Float16 Bh[128 * GP];
    __shared__ __align__(16) _Float16 Bl[128 * GP];

    const int txb = blockIdx.x, tyb = blockIdx.y;
    if (txb == 0 && tyb == 1) return;                 // below-diagonal: mirrored later
    const int tileId = (tyb == 0) ? txb : 2;
    const int b = blockIdx.z >> 3;
    const int ks = blockIdx.z & 7;
    const int r0 = tyb * 128, c0 = txb * 128;
    const bool diag = (r0 == c0);
    const float* xb = x + (long)b * 524288;

    const int t = threadIdx.x;
    const int lane = t & 63, wave = t >> 6;
    const int wy = wave >> 1, wx = wave & 1;
    const int mIn = lane & 15, quad = lane >> 4;

    f4v acc[4][4] = {};
    const int aBase = (wy * 64 + mIn) * GP + quad * 8;
    const int bBase = (wx * 64 + mIn) * GP + quad * 8;

    int kk = ks * 256;
    for (int kb = 0; kb < 8; ++kb, kk += 32) {
        #pragma unroll
        for (int i = 0; i < 4; ++i) {
            const int idx = t + (i << 8);
            const int row = idx >> 3, kq = (idx & 7) << 2;
            const float4 va = *(const float4*)&xb[(long)(r0 + row) * 2048 + kk + kq];
            half4 hv, lv;
            hv[0] = (_Float16)va.x; lv[0] = (_Float16)(va.x - (float)hv[0]);
            hv[1] = (_Float16)va.y; lv[1] = (_Float16)(va.y - (float)hv[1]);
            hv[2] = (_Float16)va.z; lv[2] = (_Float16)(va.z - (float)hv[2]);
            hv[3] = (_Float16)va.w; lv[3] = (_Float16)(va.w - (float)hv[3]);
            *(half4*)&Ah[row * GP + kq] = hv;
            *(half4*)&Al[row * GP + kq] = lv;
            if (!diag) {
                const float4 vb = *(const float4*)&xb[(long)(c0 + row) * 2048 + kk + kq];
                half4 hb, lb;
                hb[0] = (_Float16)vb.x; lb[0] = (_Float16)(vb.x - (float)hb[0]);
                hb[1] = (_Float16)vb.y; lb[1] = (_Float16)(vb.y - (float)hb[1]);
                hb[2] = (_Float16)vb.z; lb[2] = (_Float16)(vb.z - (float)hb[2]);
                hb[3] = (_Float16)vb.w; lb[3] = (_Float16)(vb.w - (float)hb[3]);
                *(half4*)&Bh[row * GP + kq] = hb;
                *(half4*)&Bl[row * GP + kq] = lb;
            }
        }
        __syncthreads();
        const _Float16* BhP = diag ? Ah : Bh;
        const _Float16* BlP = diag ? Al : Bl;
        #pragma unroll
        for (int ph = 0; ph < 3; ++ph) {
            const _Float16* As = (ph == 2) ? Al : Ah;
            const _Float16* Bs = (ph == 1) ? BlP : BhP;
            half8 af[4], bf[4];
            #pragma unroll
            for (int i = 0; i < 4; ++i) {
                af[i] = *(const half8*)&As[aBase + i * 16 * GP];
                bf[i] = *(const half8*)&Bs[bBase + i * 16 * GP];
            }
            #pragma unroll
            for (int i = 0; i < 4; ++i)
                #pragma unroll
                for (int j = 0; j < 4; ++j)
                    acc[i][j] = __builtin_amdgcn_mfma_f32_16x16x32_f16(af[i], bf[j], acc[i][j], 0, 0, 0);
        }
        __syncthreads();
    }

    float* D = Gpart + ((((long)ks * 8 + b) * 3 + tileId) << 14);
    #pragma unroll
    for (int i = 0; i < 4; ++i)
        #pragma unroll
        for (int j = 0; j < 4; ++j)
            #pragma unroll
            for (int r = 0; r < 4; ++r)
                D[((wy * 64 + i * 16 + quad * 4 + r) << 7) + (wx * 64 + j * 16 + mIn)] = acc[i][j][r];
}

// ---- reduce Gpart over ks into G ----
__launch_bounds__(256)
__global__ void reduceG_kernel(const float* __restrict__ Gpart, float* __restrict__ G) {
    const int te = blockIdx.x * 256 + threadIdx.x;     // 0..16383
    const int tile = blockIdx.y, b = blockIdx.z;
    float s = 0.0f;
    #pragma unroll
    for (int ks = 0; ks < 8; ++ks)
        s += Gpart[((((long)ks * 8 + b) * 3 + tile) << 14) + te];
    const int row = te >> 7, col = te & 127;
    const int R = row + (tile == 2 ? 128 : 0);
    const int Cc = col + (tile >= 1 ? 128 : 0);
    G[(long)b * 65536 + R * 256 + Cc] = s;
}

// ---------------- fp32 64x64 GEMM for the small C x C products ----------------
// TRANSA: A[r][k] = Amat[k*lda + r] (for W3 = Wq^T Wk). EPI: 0 plain store;
// 6: add rank-1 terms e1[b,r]*e2[col] + e3[r]*e4[b,col], then split-write f16 hi/lo.
template <bool TRANSA, int EPI>
__launch_bounds__(256)
__global__ void gemm64(const float* __restrict__ Amat, long aBatch, int lda,
                       const float* __restrict__ Bmat, long bBatch, int ldb,
                       float* __restrict__ Dmat, long dBatch, int ldd, int K,
                       const float* __restrict__ e1, const float* __restrict__ e2,
                       const float* __restrict__ e3, const float* __restrict__ e4,
                       _Float16* __restrict__ hiOut, _Float16* __restrict__ loOut) {
    constexpr int PA = 68, PB = 68;
    __shared__ float ldsA[16 * PA];
    __shared__ float ldsB[16 * PB];

    const int b = blockIdx.z;
    const int r0 = blockIdx.y * 64;
    const int j0 = blockIdx.x * 64;
    const float* A = Amat + (long)b * aBatch;
    const float* B = Bmat + (long)b * bBatch;

    const int t = threadIdx.x;
    const int tx = t & 15, ty = t >> 4;
    const int sr = t >> 2, sk = (t & 3) * 4;

    float acc[4][4] = {};
    for (int kk = 0; kk < K; kk += 16) {
        if (TRANSA) {
            const float4 a4 = *(const float4*)&A[(long)(kk + ty) * lda + r0 + tx * 4];
            *(float4*)&ldsA[ty * PA + tx * 4] = a4;
        } else {
            const float4 a4 = *(const float4*)&A[(long)(r0 + sr) * lda + kk + sk];
            ldsA[(sk + 0) * PA + sr] = a4.x;
            ldsA[(sk + 1) * PA + sr] = a4.y;
            ldsA[(sk + 2) * PA + sr] = a4.z;
            ldsA[(sk + 3) * PA + sr] = a4.w;
        }
        const float4 b4 = *(const float4*)&B[(long)(kk + ty) * ldb + j0 + tx * 4];
        *(float4*)&ldsB[ty * PB + tx * 4] = b4;
        __syncthreads();
        #pragma unroll
        for (int k = 0; k < 16; ++k) {
            const float4 a = *(const float4*)&ldsA[k * PA + ty * 4];
            const float4 bb = *(const float4*)&ldsB[k * PB + tx * 4];
            const float ar[4] = {a.x, a.y, a.z, a.w};
            const float br[4] = {bb.x, bb.y, bb.z, bb.w};
            #pragma unroll
            for (int i = 0; i < 4; ++i)
                #pragma unroll
                for (int j = 0; j < 4; ++j)
                    acc[i][j] = fmaf(ar[i], br[j], acc[i][j]);
        }
        __syncthreads();
    }

    #pragma unroll
    for (int i = 0; i < 4; ++i) {
        const int r = r0 + ty * 4 + i;
        if (EPI == 6) {
            half4 hv, lv;
            #pragma unroll
            for (int j = 0; j < 4; ++j) {
                const int col = j0 + tx * 4 + j;
                const float val = acc[i][j] + e1[(long)b * 256 + r] * e2[col] + e3[r] * e4[(long)b * 256 + col];
                hv[j] = (_Float16)val;
                lv[j] = (_Float16)(val - (float)hv[j]);
            }
            const long o = (long)b * 65536 + (long)r * 256 + j0 + tx * 4;
            *(half4*)&hiOut[o] = hv;
            *(half4*)&loOut[o] = lv;
        } else {
            float* D = Dmat + (long)b * dBatch;
            *(float4*)&D[(long)r * ldd + j0 + tx * 4] =
                make_float4(acc[i][0], acc[i][1], acc[i][2], acc[i][3]);
        }
    }
}

// ---------------- final: out = Ap x / S + cvec, f16-split MFMA ----------------
// grid (16,2,8); tile 128(c) x 128(n); K=256, BK=32
__launch_bounds__(256)
__global__ void gemmF_mfma(const _Float16* __restrict__ Aph, const _Float16* __restrict__ Apl,
                           const _Float16* __restrict__ xTh, const _Float16* __restrict__ xTl,
                           const float* __restrict__ Sptr, const float* __restrict__ cvec,
                           float* __restrict__ out) {
    __shared__ __align__(16) _Float16 Ah[128 * GP];
    __shared__ __align__(16) _Float16 Al[128 * GP];
    __shared__ __align__(16) _Float16 Bh[128 * GP];
    __shared__ __align__(16) _Float16 Bl[128 * GP];

    const int n0 = blockIdx.x * 128;
    const int c0 = blockIdx.y * 128;
    const int b = blockIdx.z;
    const _Float16* Asrc_h = Aph + (long)b * 65536;
    const _Float16* Asrc_l = Apl + (long)b * 65536;
    const _Float16* Bsrc_h = xTh + (long)b * 524288;
    const _Float16* Bsrc_l = xTl + (long)b * 524288;

    const int t = threadIdx.x;
    const int lane = t & 63, wave = t >> 6;
    const int wy = wave >> 1, wx = wave & 1;
    const int mIn = lane & 15, quad = lane >> 4;

    f4v acc[4][4] = {};
    const int aBase = (wy * 64 + mIn) * GP + quad * 8;
    const int bBase = (wx * 64 + mIn) * GP + quad * 8;

    for (int kk = 0; kk < 256; kk += 32) {
        #pragma unroll
        for (int i = 0; i < 2; ++i) {
            const int idx = t + (i << 8);
            const int row = idx >> 2, ko = (idx & 3) << 3;
            *(uint4*)&Ah[row * GP + ko] = *(const uint4*)&Asrc_h[(long)(c0 + row) * 256 + kk + ko];
            *(uint4*)&Al[row * GP + ko] = *(const uint4*)&Asrc_l[(long)(c0 + row) * 256 + kk + ko];
            *(uint4*)&Bh[row * GP + ko] = *(const uint4*)&Bsrc_h[(long)(n0 + row) * 256 + kk + ko];
            *(uint4*)&Bl[row * GP + ko] = *(const uint4*)&Bsrc_l[(long)(n0 + row) * 256 + kk + ko];
        }
        __syncthreads();
        #pragma unroll
        for (int ph = 0; ph < 3; ++ph) {
            const _Float16* As = (ph == 2) ? Al : Ah;
            const _Float16* Bs = (ph == 1) ? Bl : Bh;
            half8 af[4], bf[4];
            #pragma unroll
            for (int i = 0; i < 4; ++i) {
                af[i] = *(const half8*)&As[aBase + i * 16 * GP];
                bf[i] = *(const half8*)&Bs[bBase + i * 16 * GP];
            }
            #pragma unroll
            for (int i = 0; i < 4; ++i)
                #pragma unroll
                for (int j = 0; j < 4; ++j)
                    acc[i][j] = __builtin_amdgcn_mfma_f32_16x16x32_f16(af[i], bf[j], acc[i][j], 0, 0, 0);
        }
        __syncthreads();
    }

    const float invS = 1.0f / Sptr[0];
    float* ob = out + (long)b * 524288;
    const float* cv = cvec + b * 256;
    #pragma unroll
    for (int i = 0; i < 4; ++i)
        #pragma unroll
        for (int r = 0; r < 4; ++r) {
            const int row = c0 + wy * 64 + i * 16 + quad * 4 + r;
            const float c = cv[row];
            #pragma unroll
            for (int j = 0; j < 4; ++j) {
                const int col = n0 + wx * 64 + j * 16 + mIn;
                ob[(long)row * 2048 + col] = acc[i][j][r] * invS + c;
            }
        }
}

extern "C" void kernel_launch(void* const* d_in, const int* in_sizes, int n_in,
                              void* d_out, int out_size, void* d_ws, size_t ws_size,
                              hipStream_t stream) {
    const float* x  = (const float*)d_in[0];
    const float* Wq = (const float*)d_in[1];
    const float* bq = (const float*)d_in[2];
    const float* Wk = (const float*)d_in[3];
    const float* bk = (const float*)d_in[4];
    const float* Wv = (const float*)d_in[5];
    const float* bv = (const float*)d_in[6];
    float* out = (float*)d_out;
    float* ws  = (float*)d_ws;

    const int B = 8;
    float* G     = ws;                  // 524288
    float* T1    = ws + 524288;         // 524288
    float* W3    = ws + 1048576;        // 65536
    float* sx    = ws + 1114112;
    float* wqsx  = ws + 1116160;
    float* tq    = ws + 1118208;
    float* wvsx  = ws + 1120256;
    float* cvec  = ws + 1122304;
    float* v2    = ws + 1124352;
    float* u2    = ws + 1126400;
    float* w1    = ws + 1126656;
    float* s2    = ws + 1126912;
    float* s1    = ws + 1126920;
    float* S     = ws + 1126924;
    float* Gpart = ws + 1130496;        // 3145728 floats (12 MB)
    _Float16* fh = (_Float16*)(ws + 4276224);
    _Float16* Aph = fh;                 // 524288 halves
    _Float16* Apl = fh + 524288;
    _Float16* xTh = fh + 1048576;       // 4194304 halves
    _Float16* xTl = fh + 5242880;       // total ws use ~35 MB

    hipMemsetAsync(S, 0, sizeof(float), stream);

    rowsum_kernel<<<dim3(B * 256), 256, 0, stream>>>(x, sx);
    stats_kernel<<<dim3(B), 256, 0, stream>>>(Wq, bq, Wk, bk, Wv, sx, wqsx, tq, wvsx, S);
    prep2_kernel<<<dim3(B), 256, 0, stream>>>(Wq, Wk, bq, bk, tq, v2, u2, w1, s2, s1);
    xtsplit_kernel<<<dim3(64, 8, B), dim3(32, 8), 0, stream>>>(x, xTh, xTl);

    // W3 = Wq^T Wk
    gemm64<true, 0><<<dim3(4, 4, 1), 256, 0, stream>>>(
        Wq, 0, 256, Wk, 0, 256, W3, 0, 256, 256,
        nullptr, nullptr, nullptr, nullptr, nullptr, nullptr);

    // G = x x^T (f16-split MFMA, splitK=8)
    gemmG_mfma<<<dim3(2, 2, B * 8), 256, 0, stream>>>(x, Gpart);
    reduceG_kernel<<<dim3(64, 3, B), 256, 0, stream>>>(Gpart, G);
    mirror_kernel<<<dim3(4, 4, B), dim3(32, 8), 0, stream>>>(G);

    // T1_b = Wv G_b
    gemm64<false, 0><<<dim3(4, 4, B), 256, 0, stream>>>(
        Wv, 0, 256, G, 65536, 256, T1, 65536, 256, 256,
        nullptr, nullptr, nullptr, nullptr, nullptr, nullptr);

    // Ap_b = T1_b W3 + wvsx (x) u2 + bv (x) v2  -> f16 hi/lo split
    gemm64<false, 6><<<dim3(4, 4, B), 256, 0, stream>>>(
        T1, 65536, 256, W3, 0, 256, nullptr, 0, 256, 256,
        wvsx, u2, bv, v2, Aph, Apl);

    cvec2_kernel<<<dim3(B), 256, 0, stream>>>(T1, w1, wvsx, bv, s2, s1, S, cvec);

    // out_b = Ap_b x_b / S + cvec
    gemmF_mfma<<<dim3(16, 2, B), 256, 0, stream>>>(Aph, Apl, xTh, xTl, S, cvec, out);
}

// Round 4
// 219.441 us; speedup vs baseline: 1.3205x; 1.1087x over previous
//
#include <hip/hip_runtime.h>

// B=8, C=256, N=2048, fp32 in/out.
// attn_b = (Ap_b x_b + (M_b bk) 1^T) / S
//   Ap_b = T1_b W3 + wvsx_b (x) u2 + bv (x) v2_b      (f16 hi/lo split for final MFMA)
//   T1_b = Wv G_b,  W3 = Wq^T Wk,  G_b = x_b x_b^T (symmetric)
//   u2 = Wk^T bq, v2_b = Wk^T tq_b, tq_b = Wq sx_b + N bq, sx_b = rowsum(x_b)
//   M_b bk = T1_b w1 + wvsx_b (bq.bk) + bv (tq_b.bk),  w1 = Wq^T bk  (cvec, raw)
//   S = sum_b tq_b . (Wk sx_b + N bk)
// 6 kernel nodes total (was 13): node/serialization overhead was the round-3 residual.

typedef _Float16 half8 __attribute__((ext_vector_type(8)));
typedef _Float16 half4 __attribute__((ext_vector_type(4)));
typedef float f4v __attribute__((ext_vector_type(4)));

#define GP 40   // LDS pitch (halves) for MFMA panels

// ---------------- K1: rowsum + zero G/S  |  x transpose-split ----------------
// grid 3072: blocks 0..2047 rowsum (and zero G, 2048*256 == |G|); 2048.. transpose.
__launch_bounds__(256)
__global__ void pre_kernel(const float* __restrict__ x, float* __restrict__ sx,
                           float* __restrict__ G, float* __restrict__ S,
                           _Float16* __restrict__ xTh, _Float16* __restrict__ xTl) {
    const int blk = blockIdx.x, t = threadIdx.x;
    if (blk < 2048) {
        G[blk * 256 + t] = 0.0f;
        if (blk == 0 && t == 0) S[0] = 0.0f;
        const float* xr = x + (long)blk * 2048;
        float s = 0.0f;
        #pragma unroll
        for (int i = 0; i < 8; ++i) s += xr[t + 256 * i];
        __shared__ float red[256];
        red[t] = s; __syncthreads();
        for (int h = 128; h > 0; h >>= 1) { if (t < h) red[t] += red[t + h]; __syncthreads(); }
        if (t == 0) sx[blk] = red[0];
    } else {
        const int tile = blk - 2048;            // 0..1023: 64x64 tiles
        const int b  = tile >> 7;
        const int tb = tile & 127;
        const int n0 = (tb & 31) * 64;
        const int c0 = (tb >> 5) * 64;
        __shared__ float tl[64 * 65];
        const float* xb = x + (long)b * 524288;
        #pragma unroll
        for (int p = 0; p < 16; ++p) {
            const int idx = t + p * 256;
            const int r = idx >> 6, c = idx & 63;
            tl[r * 65 + c] = xb[(long)(c0 + r) * 2048 + n0 + c];
        }
        __syncthreads();
        #pragma unroll
        for (int p = 0; p < 16; ++p) {
            const int idx = t + p * 256;
            const int n = idx >> 6, c = idx & 63;
            const float v = tl[c * 65 + n];
            const _Float16 h = (_Float16)v;
            const _Float16 l = (_Float16)(v - (float)h);
            const long o = (long)b * 524288 + (long)(n0 + n) * 256 + c0 + c;
            xTh[o] = h; xTl[o] = l;
        }
    }
}

// ---------------- K2: per-batch stats + cvec init  |  W3 = Wq^T Wk ----------------
// grid 24: blocks 0..7 stats for batch b; blocks 8..23 W3 64x64 tiles.
__launch_bounds__(256)
__global__ void prep_kernel(const float* __restrict__ Wq, const float* __restrict__ bq,
                            const float* __restrict__ Wk, const float* __restrict__ bk,
                            const float* __restrict__ Wv, const float* __restrict__ bv,
                            const float* __restrict__ sx, float* __restrict__ wvsx,
                            float* __restrict__ v2, float* __restrict__ u2,
                            float* __restrict__ w1, float* __restrict__ cvec,
                            float* __restrict__ S, float* __restrict__ W3) {
    const int blk = blockIdx.x, t = threadIdx.x;
    if (blk < 8) {
        const int b = blk, o = t;
        __shared__ float ssx[256], stq[256], red[256];
        ssx[o] = sx[b * 256 + o];
        __syncthreads();
        float aq = 0.0f, ak = 0.0f, av = 0.0f;
        const float4* q4 = (const float4*)(Wq + (long)o * 256);
        const float4* k4 = (const float4*)(Wk + (long)o * 256);
        const float4* v4 = (const float4*)(Wv + (long)o * 256);
        #pragma unroll 4
        for (int c = 0; c < 64; ++c) {
            const float4 wq = q4[c], wk = k4[c], wv = v4[c];
            const float s0 = ssx[4 * c], s1 = ssx[4 * c + 1], s2 = ssx[4 * c + 2], s3 = ssx[4 * c + 3];
            aq = fmaf(wq.x, s0, fmaf(wq.y, s1, fmaf(wq.z, s2, fmaf(wq.w, s3, aq))));
            ak = fmaf(wk.x, s0, fmaf(wk.y, s1, fmaf(wk.z, s2, fmaf(wk.w, s3, ak))));
            av = fmaf(wv.x, s0, fmaf(wv.y, s1, fmaf(wv.z, s2, fmaf(wv.w, s3, av))));
        }
        const float bko = bk[o], bqo = bq[o], bvo = bv[o];
        const float tqo = aq + 2048.0f * bqo;
        const float tko = ak + 2048.0f * bko;
        stq[o] = tqo;
        wvsx[b * 256 + o] = av;
        red[o] = tqo * tko; __syncthreads();
        for (int h = 128; h > 0; h >>= 1) { if (t < h) red[t] += red[t + h]; __syncthreads(); }
        if (t == 0) atomicAdd(S, red[0]);
        __syncthreads();
        // v2[b,o] = sum_c Wk[c,o] * tq[c]   (coalesced: lane o contiguous)
        float a = 0.0f;
        #pragma unroll 4
        for (int c = 0; c < 256; ++c) a = fmaf(Wk[(long)c * 256 + o], stq[c], a);
        v2[b * 256 + o] = a;
        // s2 = tq . bk
        red[o] = tqo * bko; __syncthreads();
        for (int h = 128; h > 0; h >>= 1) { if (t < h) red[t] += red[t + h]; __syncthreads(); }
        const float s2v = red[0]; __syncthreads();
        // s1 = bq . bk (computed redundantly per block)
        red[o] = bqo * bko; __syncthreads();
        for (int h = 128; h > 0; h >>= 1) { if (t < h) red[t] += red[t + h]; __syncthreads(); }
        const float s1v = red[0];
        cvec[b * 256 + o] = av * s1v + bvo * s2v;   // raw (not /S); t1 adds T1.w1
        if (b == 0) {
            float u = 0.0f, w = 0.0f;
            #pragma unroll 4
            for (int c = 0; c < 256; ++c) {
                u = fmaf(Wk[(long)c * 256 + o], bq[c], u);
                w = fmaf(Wq[(long)c * 256 + o], bk[c], w);
            }
            u2[o] = u; w1[o] = w;
        }
    } else {
        const int tile = blk - 8;
        const int r0 = (tile >> 2) * 64, j0 = (tile & 3) * 64;
        __shared__ float ldsA[16 * 68], ldsB[16 * 68];
        const int tx = t & 15, ty = t >> 4;
        float acc[4][4] = {};
        for (int kk = 0; kk < 256; kk += 16) {
            *(float4*)&ldsA[ty * 68 + tx * 4] = *(const float4*)&Wq[(long)(kk + ty) * 256 + r0 + tx * 4];
            *(float4*)&ldsB[ty * 68 + tx * 4] = *(const float4*)&Wk[(long)(kk + ty) * 256 + j0 + tx * 4];
            __syncthreads();
            #pragma unroll
            for (int k = 0; k < 16; ++k) {
                const float4 av4 = *(const float4*)&ldsA[k * 68 + ty * 4];
                const float4 bv4 = *(const float4*)&ldsB[k * 68 + tx * 4];
                const float ar[4] = {av4.x, av4.y, av4.z, av4.w};
                const float br[4] = {bv4.x, bv4.y, bv4.z, bv4.w};
                #pragma unroll
                for (int i = 0; i < 4; ++i)
                    #pragma unroll
                    for (int j = 0; j < 4; ++j)
                        acc[i][j] = fmaf(ar[i], br[j], acc[i][j]);
            }
            __syncthreads();
        }
        #pragma unroll
        for (int i = 0; i < 4; ++i)
            *(float4*)&W3[(long)(r0 + ty * 4 + i) * 256 + j0 + tx * 4] =
                make_float4(acc[i][0], acc[i][1], acc[i][2], acc[i][3]);
    }
}

// ---------------- K3: G += x x^T (f16-split MFMA, splitK=8, symmetric) ----------------
// grid (3, 64): tileId {0:(0,0) diag, 1:(0,128) offdiag+mirror, 2:(128,128) diag}
__launch_bounds__(256)
__global__ void gemmG_mfma(const float* __restrict__ x, float* __restrict__ G) {
    __shared__ __align__(16) _Float16 Ah[128 * GP];
    __shared__ __align__(16) _Float16 Al[128 * GP];
    __shared__ __align__(16) _Float16 Bh[128 * GP];
    __shared__ __align__(16) _Float16 Bl[128 * GP];

    const int tileId = blockIdx.x;
    const int b  = blockIdx.y >> 3;
    const int ks = blockIdx.y & 7;
    const int r0 = (tileId == 2) ? 128 : 0;
    const int c0 = (tileId == 0) ? 0 : 128;
    const bool diag = (tileId != 1);
    const float* xb = x + (long)b * 524288;

    const int t = threadIdx.x;
    const int lane = t & 63, wave = t >> 6;
    const int wy = wave >> 1, wx = wave & 1;
    const int mIn = lane & 15, quad = lane >> 4;

    f4v acc[4][4] = {};
    const int aBase = (wy * 64 + mIn) * GP + quad * 8;
    const int bBase = (wx * 64 + mIn) * GP + quad * 8;

    int kk = ks * 256;
    for (int kb = 0; kb < 8; ++kb, kk += 32) {
        #pragma unroll
        for (int i = 0; i < 4; ++i) {
            const int idx = t + (i << 8);
            const int row = idx >> 3, kq = (idx & 7) << 2;
            const float4 va = *(const float4*)&xb[(long)(r0 + row) * 2048 + kk + kq];
            half4 hv, lv;
            hv[0] = (_Float16)va.x; lv[0] = (_Float16)(va.x - (float)hv[0]);
            hv[1] = (_Float16)va.y; lv[1] = (_Float16)(va.y - (float)hv[1]);
            hv[2] = (_Float16)va.z; lv[2] = (_Float16)(va.z - (float)hv[2]);
            hv[3] = (_Float16)va.w; lv[3] = (_Float16)(va.w - (float)hv[3]);
            *(half4*)&Ah[row * GP + kq] = hv;
            *(half4*)&Al[row * GP + kq] = lv;
            if (!diag) {
                const float4 vb = *(const float4*)&xb[(long)(c0 + row) * 2048 + kk + kq];
                half4 hb, lb;
                hb[0] = (_Float16)vb.x; lb[0] = (_Float16)(vb.x - (float)hb[0]);
                hb[1] = (_Float16)vb.y; lb[1] = (_Float16)(vb.y - (float)hb[1]);
                hb[2] = (_Float16)vb.z; lb[2] = (_Float16)(vb.z - (float)hb[2]);
                hb[3] = (_Float16)vb.w; lb[3] = (_Float16)(vb.w - (float)hb[3]);
                *(half4*)&Bh[row * GP + kq] = hb;
                *(half4*)&Bl[row * GP + kq] = lb;
            }
        }
        __syncthreads();
        const _Float16* BhP = diag ? Ah : Bh;
        const _Float16* BlP = diag ? Al : Bl;
        #pragma unroll
        for (int ph = 0; ph < 3; ++ph) {
            const _Float16* As = (ph == 2) ? Al : Ah;
            const _Float16* Bs = (ph == 1) ? BlP : BhP;
            half8 af[4], bf[4];
            #pragma unroll
            for (int i = 0; i < 4; ++i) {
                af[i] = *(const half8*)&As[aBase + i * 16 * GP];
                bf[i] = *(const half8*)&Bs[bBase + i * 16 * GP];
            }
            #pragma unroll
            for (int i = 0; i < 4; ++i)
                #pragma unroll
                for (int j = 0; j < 4; ++j)
                    acc[i][j] = __builtin_amdgcn_mfma_f32_16x16x32_f16(af[i], bf[j], acc[i][j], 0, 0, 0);
        }
        __syncthreads();
    }

    float* Gb = G + (long)b * 65536;
    #pragma unroll
    for (int i = 0; i < 4; ++i)
        #pragma unroll
        for (int j = 0; j < 4; ++j)
            #pragma unroll
            for (int r = 0; r < 4; ++r) {
                const int row = r0 + wy * 64 + i * 16 + quad * 4 + r;
                const int col = c0 + wx * 64 + j * 16 + mIn;
                atomicAdd(&Gb[row * 256 + col], acc[i][j][r]);
                if (tileId == 1) atomicAdd(&Gb[col * 256 + row], acc[i][j][r]);
            }
}

// ---------------- K4: T1 = Wv G (fp32) + cvec += T1 . w1 ----------------
__launch_bounds__(256)
__global__ void t1_kernel(const float* __restrict__ Wv, const float* __restrict__ G,
                          const float* __restrict__ w1, float* __restrict__ T1,
                          float* __restrict__ cvec) {
    __shared__ float ldsA[16 * 68], ldsB[16 * 68];
    const int b = blockIdx.z;
    const int r0 = blockIdx.y * 64, j0 = blockIdx.x * 64;
    const float* B = G + (long)b * 65536;
    const int t = threadIdx.x, tx = t & 15, ty = t >> 4;
    const int sr = t >> 2, sk = (t & 3) * 4;
    float acc[4][4] = {};
    for (int kk = 0; kk < 256; kk += 16) {
        const float4 a4 = *(const float4*)&Wv[(long)(r0 + sr) * 256 + kk + sk];
        ldsA[(sk + 0) * 68 + sr] = a4.x;
        ldsA[(sk + 1) * 68 + sr] = a4.y;
        ldsA[(sk + 2) * 68 + sr] = a4.z;
        ldsA[(sk + 3) * 68 + sr] = a4.w;
        *(float4*)&ldsB[ty * 68 + tx * 4] = *(const float4*)&B[(long)(kk + ty) * 256 + j0 + tx * 4];
        __syncthreads();
        #pragma unroll
        for (int k = 0; k < 16; ++k) {
            const float4 av4 = *(const float4*)&ldsA[k * 68 + ty * 4];
            const float4 bv4 = *(const float4*)&ldsB[k * 68 + tx * 4];
            const float ar[4] = {av4.x, av4.y, av4.z, av4.w};
            const float br[4] = {bv4.x, bv4.y, bv4.z, bv4.w};
            #pragma unroll
            for (int i = 0; i < 4; ++i)
                #pragma unroll
                for (int j = 0; j < 4; ++j)
                    acc[i][j] = fmaf(ar[i], br[j], acc[i][j]);
        }
        __syncthreads();
    }
    float* D = T1 + (long)b * 65536;
    float w4[4];
    *(float4*)w4 = *(const float4*)&w1[j0 + tx * 4];
    #pragma unroll
    for (int i = 0; i < 4; ++i) {
        const int r = r0 + ty * 4 + i;
        *(float4*)&D[(long)r * 256 + j0 + tx * 4] =
            make_float4(acc[i][0], acc[i][1], acc[i][2], acc[i][3]);
        float p = acc[i][0] * w4[0] + acc[i][1] * w4[1] + acc[i][2] * w4[2] + acc[i][3] * w4[3];
        p += __shfl_xor(p, 1); p += __shfl_xor(p, 2);
        p += __shfl_xor(p, 4); p += __shfl_xor(p, 8);
        if (tx == 0) atomicAdd(&cvec[b * 256 + r], p);
    }
}

// ---------------- K5: Ap = T1 W3 + wvsx(x)u2 + bv(x)v2 -> f16 hi/lo ----------------
__launch_bounds__(256)
__global__ void ap_kernel(const float* __restrict__ T1, const float* __restrict__ W3,
                          const float* __restrict__ wvsx, const float* __restrict__ u2,
                          const float* __restrict__ bv, const float* __restrict__ v2,
                          _Float16* __restrict__ Aph, _Float16* __restrict__ Apl) {
    __shared__ float ldsA[16 * 68], ldsB[16 * 68];
    const int b = blockIdx.z;
    const int r0 = blockIdx.y * 64, j0 = blockIdx.x * 64;
    const float* A = T1 + (long)b * 65536;
    const int t = threadIdx.x, tx = t & 15, ty = t >> 4;
    const int sr = t >> 2, sk = (t & 3) * 4;
    float acc[4][4] = {};
    for (int kk = 0; kk < 256; kk += 16) {
        const float4 a4 = *(const float4*)&A[(long)(r0 + sr) * 256 + kk + sk];
        ldsA[(sk + 0) * 68 + sr] = a4.x;
        ldsA[(sk + 1) * 68 + sr] = a4.y;
        ldsA[(sk + 2) * 68 + sr] = a4.z;
        ldsA[(sk + 3) * 68 + sr] = a4.w;
        *(float4*)&ldsB[ty * 68 + tx * 4] = *(const float4*)&W3[(long)(kk + ty) * 256 + j0 + tx * 4];
        __syncthreads();
        #pragma unroll
        for (int k = 0; k < 16; ++k) {
            const float4 av4 = *(const float4*)&ldsA[k * 68 + ty * 4];
            const float4 bv4 = *(const float4*)&ldsB[k * 68 + tx * 4];
            const float ar[4] = {av4.x, av4.y, av4.z, av4.w};
            const float br[4] = {bv4.x, bv4.y, bv4.z, bv4.w};
            #pragma unroll
            for (int i = 0; i < 4; ++i)
                #pragma unroll
                for (int j = 0; j < 4; ++j)
                    acc[i][j] = fmaf(ar[i], br[j], acc[i][j]);
        }
        __syncthreads();
    }
    #pragma unroll
    for (int i = 0; i < 4; ++i) {
        const int r = r0 + ty * 4 + i;
        const float e1 = wvsx[b * 256 + r], e3 = bv[r];
        half4 hv, lv;
        #pragma unroll
        for (int j = 0; j < 4; ++j) {
            const int col = j0 + tx * 4 + j;
            const float val = acc[i][j] + e1 * u2[col] + e3 * v2[b * 256 + col];
            hv[j] = (_Float16)val;
            lv[j] = (_Float16)(val - (float)hv[j]);
        }
        const long o = (long)b * 65536 + (long)r * 256 + j0 + tx * 4;
        *(half4*)&Aph[o] = hv;
        *(half4*)&Apl[o] = lv;
    }
}

// ---------------- K6: out = (Ap x + cvec 1^T) / S  (f16-split MFMA) ----------------
__launch_bounds__(256)
__global__ void gemmF_mfma(const _Float16* __restrict__ Aph, const _Float16* __restrict__ Apl,
                           const _Float16* __restrict__ xTh, const _Float16* __restrict__ xTl,
                           const float* __restrict__ Sptr, const float* __restrict__ cvec,
                           float* __restrict__ out) {
    __shared__ __align__(16) _Float16 Ah[128 * GP];
    __shared__ __align__(16) _Float16 Al[128 * GP];
    __shared__ __align__(16) _Float16 Bh[128 * GP];
    __shared__ __align__(16) _Float16 Bl[128 * GP];

    const int n0 = blockIdx.x * 128;
    const int c0 = blockIdx.y * 128;
    const int b = blockIdx.z;
    const _Float16* Asrc_h = Aph + (long)b * 65536;
    const _Float16* Asrc_l = Apl + (long)b * 65536;
    const _Float16* Bsrc_h = xTh + (long)b * 524288;
    const _Float16* Bsrc_l = xTl + (long)b * 524288;

    const int t = threadIdx.x;
    const int lane = t & 63, wave = t >> 6;
    const int wy = wave >> 1, wx = wave & 1;
    const int mIn = lane & 15, quad = lane >> 4;

    f4v acc[4][4] = {};
    const int aBase = (wy * 64 + mIn) * GP + quad * 8;
    const int bBase = (wx * 64 + mIn) * GP + quad * 8;

    for (int kk = 0; kk < 256; kk += 32) {
        #pragma unroll
        for (int i = 0; i < 2; ++i) {
            const int idx = t + (i << 8);
            const int row = idx >> 2, ko = (idx & 3) << 3;
            *(uint4*)&Ah[row * GP + ko] = *(const uint4*)&Asrc_h[(long)(c0 + row) * 256 + kk + ko];
            *(uint4*)&Al[row * GP + ko] = *(const uint4*)&Asrc_l[(long)(c0 + row) * 256 + kk + ko];
            *(uint4*)&Bh[row * GP + ko] = *(const uint4*)&Bsrc_h[(long)(n0 + row) * 256 + kk + ko];
            *(uint4*)&Bl[row * GP + ko] = *(const uint4*)&Bsrc_l[(long)(n0 + row) * 256 + kk + ko];
        }
        __syncthreads();
        #pragma unroll
        for (int ph = 0; ph < 3; ++ph) {
            const _Float16* As = (ph == 2) ? Al : Ah;
            const _Float16* Bs = (ph == 1) ? Bl : Bh;
            half8 af[4], bf[4];
            #pragma unroll
            for (int i = 0; i < 4; ++i) {
                af[i] = *(const half8*)&As[aBase + i * 16 * GP];
                bf[i] = *(const half8*)&Bs[bBase + i * 16 * GP];
            }
            #pragma unroll
            for (int i = 0; i < 4; ++i)
                #pragma unroll
                for (int j = 0; j < 4; ++j)
                    acc[i][j] = __builtin_amdgcn_mfma_f32_16x16x32_f16(af[i], bf[j], acc[i][j], 0, 0, 0);
        }
        __syncthreads();
    }

    const float invS = 1.0f / Sptr[0];
    float* ob = out + (long)b * 524288;
    const float* cv = cvec + b * 256;
    #pragma unroll
    for (int i = 0; i < 4; ++i)
        #pragma unroll
        for (int r = 0; r < 4; ++r) {
            const int row = c0 + wy * 64 + i * 16 + quad * 4 + r;
            const float c = cv[row];
            #pragma unroll
            for (int j = 0; j < 4; ++j) {
                const int col = n0 + wx * 64 + j * 16 + mIn;
                ob[(long)row * 2048 + col] = (acc[i][j][r] + c) * invS;
            }
        }
}

extern "C" void kernel_launch(void* const* d_in, const int* in_sizes, int n_in,
                              void* d_out, int out_size, void* d_ws, size_t ws_size,
                              hipStream_t stream) {
    const float* x  = (const float*)d_in[0];
    const float* Wq = (const float*)d_in[1];
    const float* bq = (const float*)d_in[2];
    const float* Wk = (const float*)d_in[3];
    const float* bk = (const float*)d_in[4];
    const float* Wv = (const float*)d_in[5];
    const float* bv = (const float*)d_in[6];
    float* out = (float*)d_out;
    float* ws  = (float*)d_ws;

    const int B = 8;
    float* G    = ws;                 // 524288 floats, zeroed by pre_kernel
    float* T1   = ws + 524288;        // 524288
    float* W3   = ws + 1048576;       // 65536
    float* sx   = ws + 1114112;       // 2048
    float* wvsx = ws + 1116160;       // 2048
    float* v2   = ws + 1118208;       // 2048
    float* cvec = ws + 1120256;       // 2048
    float* u2   = ws + 1122304;       // 256
    float* w1   = ws + 1122560;       // 256
    float* S    = ws + 1122816;       // 1
    _Float16* fh = (_Float16*)(ws + 1122848);
    _Float16* xTh = fh;               // 4194304 halves
    _Float16* xTl = fh + 4194304;
    _Float16* Aph = fh + 8388608;     // 524288 halves
    _Float16* Apl = fh + 8912896;     // total ws use ~23.4 MB

    pre_kernel<<<dim3(3072), 256, 0, stream>>>(x, sx, G, S, xTh, xTl);
    prep_kernel<<<dim3(24), 256, 0, stream>>>(Wq, bq, Wk, bk, Wv, bv, sx,
                                              wvsx, v2, u2, w1, cvec, S, W3);
    gemmG_mfma<<<dim3(3, 64), 256, 0, stream>>>(x, G);
    t1_kernel<<<dim3(4, 4, B), 256, 0, stream>>>(Wv, G, w1, T1, cvec);
    ap_kernel<<<dim3(4, 4, B), 256, 0, stream>>>(T1, W3, wvsx, u2, bv, v2, Aph, Apl);
    gemmF_mfma<<<dim3(16, 2, B), 256, 0, stream>>>(Aph, Apl, xTh, xTl, S, cvec, out);
}

// Round 5
// 182.419 us; speedup vs baseline: 1.5885x; 1.2030x over previous
//
#include <hip/hip_runtime.h>

// B=8, C=256, N=2048, fp32 in/out.
// attn_b = (Ap_b x_b + cvec_b 1^T) / S
//   Ap_b = T1_b W3 + wvsx_b (x) u2 + bv (x) v2_b      (f16 hi/lo split for final MFMA)
//   T1_b = Wv G_b,  W3 = Wq^T Wk,  G_b = x_b x_b^T (symmetric)
//   u2 = Wk^T bq, w1 = Wq^T bk, s1 = bq.bk, sx_b = rowsum(x_b)
//   v2_b = W3^T sx_b + N u2          (= Wk^T tq_b)
//   S    = sum_b [ (W3^T sx).sx + N sx.(w1+u2) + N^2 s1 ]
//   s2_b = sx.w1 + N s1;  cvec_b = wvsx*s1 + bv*s2 + T1.w1 (added by t1)
// G path: splitK=8 partials in exclusive Gpart slices (NO atomics); t1 folds the
// 8-way reduce into its B staging. gemmG pipelines global loads behind MFMA.

typedef _Float16 half8 __attribute__((ext_vector_type(8)));
typedef _Float16 half4 __attribute__((ext_vector_type(4)));
typedef float f4v __attribute__((ext_vector_type(4)));

#define GP 40   // LDS pitch (halves) for MFMA panels

// ---------------- K1: rowsum + zero S  |  x transpose-split ----------------
__launch_bounds__(256)
__global__ void pre_kernel(const float* __restrict__ x, float* __restrict__ sx,
                           float* __restrict__ S,
                           _Float16* __restrict__ xTh, _Float16* __restrict__ xTl) {
    const int blk = blockIdx.x, t = threadIdx.x;
    if (blk < 2048) {
        if (blk == 0 && t == 0) S[0] = 0.0f;
        const float* xr = x + (long)blk * 2048;
        float s = 0.0f;
        #pragma unroll
        for (int i = 0; i < 8; ++i) s += xr[t + 256 * i];
        __shared__ float red[256];
        red[t] = s; __syncthreads();
        for (int h = 128; h > 0; h >>= 1) { if (t < h) red[t] += red[t + h]; __syncthreads(); }
        if (t == 0) sx[blk] = red[0];
    } else {
        const int tile = blk - 2048;            // 0..1023: 64x64 tiles
        const int b  = tile >> 7;
        const int tb = tile & 127;
        const int n0 = (tb & 31) * 64;
        const int c0 = (tb >> 5) * 64;
        __shared__ float tl[64 * 65];
        const float* xb = x + (long)b * 524288;
        #pragma unroll
        for (int p = 0; p < 16; ++p) {
            const int idx = t + p * 256;
            const int r = idx >> 6, c = idx & 63;
            tl[r * 65 + c] = xb[(long)(c0 + r) * 2048 + n0 + c];
        }
        __syncthreads();
        #pragma unroll
        for (int p = 0; p < 16; ++p) {
            const int idx = t + p * 256;
            const int n = idx >> 6, c = idx & 63;
            const float v = tl[c * 65 + n];
            const _Float16 h = (_Float16)v;
            const _Float16 l = (_Float16)(v - (float)h);
            const long o = (long)b * 524288 + (long)(n0 + n) * 256 + c0 + c;
            xTh[o] = h; xTl[o] = l;
        }
    }
}

// ---------------- K2: W3 = Wq^T Wk | u2,w1,s1 | wvsx (skinny GEMM) ----------------
// grid 21: blocks 0..15 W3 tiles; 16: u2/w1/s1; 17..20: wvsx rows.
__launch_bounds__(256)
__global__ void prep1_kernel(const float* __restrict__ Wq, const float* __restrict__ Wk,
                             const float* __restrict__ Wv, const float* __restrict__ bq,
                             const float* __restrict__ bk, const float* __restrict__ sx,
                             float* __restrict__ W3, float* __restrict__ u2,
                             float* __restrict__ w1, float* __restrict__ s1,
                             float* __restrict__ wvsx) {
    const int blk = blockIdx.x, t = threadIdx.x;
    if (blk < 16) {
        const int r0 = (blk >> 2) * 64, j0 = (blk & 3) * 64;
        __shared__ float ldsA[16 * 68], ldsB[16 * 68];
        const int tx = t & 15, ty = t >> 4;
        float acc[4][4] = {};
        for (int kk = 0; kk < 256; kk += 16) {
            *(float4*)&ldsA[ty * 68 + tx * 4] = *(const float4*)&Wq[(long)(kk + ty) * 256 + r0 + tx * 4];
            *(float4*)&ldsB[ty * 68 + tx * 4] = *(const float4*)&Wk[(long)(kk + ty) * 256 + j0 + tx * 4];
            __syncthreads();
            #pragma unroll
            for (int k = 0; k < 16; ++k) {
                const float4 av4 = *(const float4*)&ldsA[k * 68 + ty * 4];
                const float4 bv4 = *(const float4*)&ldsB[k * 68 + tx * 4];
                const float ar[4] = {av4.x, av4.y, av4.z, av4.w};
                const float br[4] = {bv4.x, bv4.y, bv4.z, bv4.w};
                #pragma unroll
                for (int i = 0; i < 4; ++i)
                    #pragma unroll
                    for (int j = 0; j < 4; ++j)
                        acc[i][j] = fmaf(ar[i], br[j], acc[i][j]);
            }
            __syncthreads();
        }
        #pragma unroll
        for (int i = 0; i < 4; ++i)
            *(float4*)&W3[(long)(r0 + ty * 4 + i) * 256 + j0 + tx * 4] =
                make_float4(acc[i][0], acc[i][1], acc[i][2], acc[i][3]);
    } else if (blk == 16) {
        __shared__ float sbq[256], sbk[256], red[256];
        sbq[t] = bq[t]; sbk[t] = bk[t];
        __syncthreads();
        float u = 0.0f, w = 0.0f;
        #pragma unroll 8
        for (int c = 0; c < 256; ++c) {
            u = fmaf(Wk[(long)c * 256 + t], sbq[c], u);   // coalesced: lane t contiguous
            w = fmaf(Wq[(long)c * 256 + t], sbk[c], w);
        }
        u2[t] = u; w1[t] = w;
        red[t] = sbq[t] * sbk[t]; __syncthreads();
        for (int h = 128; h > 0; h >>= 1) { if (t < h) red[t] += red[t + h]; __syncthreads(); }
        if (t == 0) s1[0] = red[0];
    } else {
        // wvsx[b, r0w + r] = sum_c Wv[r0w+r, c] * sx[b, c]
        const int r0w = (blk - 17) * 64;
        __shared__ float wtile[64 * 256];
        __shared__ float sxs[2048];
        #pragma unroll
        for (int p = 0; p < 16; ++p) {
            const int idx = t + p * 256;                // float4 index 0..4095
            const int row = idx >> 6, f4 = idx & 63;
            *(float4*)&wtile[row * 256 + f4 * 4] = *(const float4*)&Wv[(long)(r0w + row) * 256 + f4 * 4];
        }
        #pragma unroll
        for (int p = 0; p < 2; ++p) {
            const int idx = t + p * 256;
            *(float4*)&sxs[idx * 4] = *(const float4*)&sx[idx * 4];
        }
        __syncthreads();
        const int r = t >> 2, q = t & 3;
        float acc[8] = {};
        for (int ci = 0; ci < 64; ++ci) {
            const float wv = wtile[r * 256 + q * 64 + ci];
            #pragma unroll
            for (int b = 0; b < 8; ++b) acc[b] = fmaf(wv, sxs[b * 256 + q * 64 + ci], acc[b]);
        }
        #pragma unroll
        for (int b = 0; b < 8; ++b) {
            acc[b] += __shfl_xor(acc[b], 1);
            acc[b] += __shfl_xor(acc[b], 2);
        }
        if (q == 0) {
            #pragma unroll
            for (int b = 0; b < 8; ++b) wvsx[b * 256 + r0w + r] = acc[b];
        }
    }
}

// ---------------- K3: per-batch v2, S, cvec init (all coalesced) ----------------
__launch_bounds__(256)
__global__ void prep2_kernel(const float* __restrict__ W3, const float* __restrict__ sx,
                             const float* __restrict__ u2, const float* __restrict__ w1,
                             const float* __restrict__ s1p, const float* __restrict__ bv,
                             const float* __restrict__ wvsx, float* __restrict__ v2,
                             float* __restrict__ cvec, float* __restrict__ S) {
    const int b = blockIdx.x, j = threadIdx.x;
    __shared__ float ssx[256], red[256];
    __shared__ float sd1, sd2, sd3;
    ssx[j] = sx[b * 256 + j];
    __syncthreads();
    float vr = 0.0f;
    #pragma unroll 8
    for (int c = 0; c < 256; ++c) vr = fmaf(W3[(long)c * 256 + j], ssx[c], vr);  // coalesced
    const float u = u2[j], w = w1[j], sj = ssx[j];
    v2[b * 256 + j] = vr + 2048.0f * u;
    red[j] = vr * sj; __syncthreads();
    for (int h = 128; h > 0; h >>= 1) { if (j < h) red[j] += red[j + h]; __syncthreads(); }
    if (j == 0) sd1 = red[0];
    __syncthreads();
    red[j] = sj * w; __syncthreads();
    for (int h = 128; h > 0; h >>= 1) { if (j < h) red[j] += red[j + h]; __syncthreads(); }
    if (j == 0) sd2 = red[0];
    __syncthreads();
    red[j] = sj * u; __syncthreads();
    for (int h = 128; h > 0; h >>= 1) { if (j < h) red[j] += red[j + h]; __syncthreads(); }
    if (j == 0) sd3 = red[0];
    __syncthreads();
    const float s1v = s1p[0];
    if (j == 0) atomicAdd(S, sd1 + 2048.0f * (sd2 + sd3) + 4194304.0f * s1v);
    const float s2v = sd2 + 2048.0f * s1v;
    cvec[b * 256 + j] = wvsx[b * 256 + j] * s1v + bv[j] * s2v;
}

// ---------------- K4: Gpart[ks,b] = x x^T slice (f16-split MFMA, pipelined) ----------------
// grid (3, 64): tileId {0:ul diag, 1:ur offdiag (+mirrored ll), 2:lr diag}; y: b=y>>3, ks=y&7
__launch_bounds__(256)
__global__ void gemmG_mfma(const float* __restrict__ x, float* __restrict__ Gpart) {
    __shared__ __align__(16) _Float16 Ah[128 * GP];
    __shared__ __align__(16) _Float16 Al[128 * GP];
    __shared__ __align__(16) _Float16 Bh[128 * GP];
    __shared__ __align__(16) _Float16 Bl[128 * GP];

    const int tileId = blockIdx.x;
    const int b  = blockIdx.y >> 3;
    const int ks = blockIdx.y & 7;
    const int r0 = (tileId == 2) ? 128 : 0;
    const int c0 = (tileId == 0) ? 0 : 128;
    const bool diag = (tileId != 1);
    const float* xb = x + (long)b * 524288;

    const int t = threadIdx.x;
    const int lane = t & 63, wave = t >> 6;
    const int wy = wave >> 1, wx = wave & 1;
    const int mIn = lane & 15, quad = lane >> 4;

    f4v acc[4][4] = {};
    const int aBase = (wy * 64 + mIn) * GP + quad * 8;
    const int bBase = (wx * 64 + mIn) * GP + quad * 8;
    const int srow = t >> 3;          // 0..31
    const int skq  = (t & 7) * 4;     // 0..28

    float4 pa[4], pb[4];
    int kk = ks * 256;
    #pragma unroll
    for (int i = 0; i < 4; ++i) {
        pa[i] = *(const float4*)&xb[(long)(r0 + srow + i * 32) * 2048 + kk + skq];
        if (!diag) pb[i] = *(const float4*)&xb[(long)(c0 + srow + i * 32) * 2048 + kk + skq];
    }

    for (int kb = 0; kb < 8; ++kb) {
        if (kb) __syncthreads();                    // prev MFMA reads done
        #pragma unroll
        for (int i = 0; i < 4; ++i) {
            const int row = srow + i * 32;
            half4 hv, lv;
            hv[0] = (_Float16)pa[i].x; lv[0] = (_Float16)(pa[i].x - (float)hv[0]);
            hv[1] = (_Float16)pa[i].y; lv[1] = (_Float16)(pa[i].y - (float)hv[1]);
            hv[2] = (_Float16)pa[i].z; lv[2] = (_Float16)(pa[i].z - (float)hv[2]);
            hv[3] = (_Float16)pa[i].w; lv[3] = (_Float16)(pa[i].w - (float)hv[3]);
            *(half4*)&Ah[row * GP + skq] = hv;
            *(half4*)&Al[row * GP + skq] = lv;
            if (!diag) {
                half4 hb, lb;
                hb[0] = (_Float16)pb[i].x; lb[0] = (_Float16)(pb[i].x - (float)hb[0]);
                hb[1] = (_Float16)pb[i].y; lb[1] = (_Float16)(pb[i].y - (float)hb[1]);
                hb[2] = (_Float16)pb[i].z; lb[2] = (_Float16)(pb[i].z - (float)hb[2]);
                hb[3] = (_Float16)pb[i].w; lb[3] = (_Float16)(pb[i].w - (float)hb[3]);
                *(half4*)&Bh[row * GP + skq] = hb;
                *(half4*)&Bl[row * GP + skq] = lb;
            }
        }
        __syncthreads();                            // staging visible
        kk += 32;
        if (kb < 7) {                               // prefetch next k-block (overlaps MFMA)
            #pragma unroll
            for (int i = 0; i < 4; ++i) {
                pa[i] = *(const float4*)&xb[(long)(r0 + srow + i * 32) * 2048 + kk + skq];
                if (!diag) pb[i] = *(const float4*)&xb[(long)(c0 + srow + i * 32) * 2048 + kk + skq];
            }
        }
        const _Float16* BhP = diag ? Ah : Bh;
        const _Float16* BlP = diag ? Al : Bl;
        #pragma unroll
        for (int ph = 0; ph < 3; ++ph) {
            const _Float16* As = (ph == 2) ? Al : Ah;
            const _Float16* Bs = (ph == 1) ? BlP : BhP;
            half8 af[4], bf[4];
            #pragma unroll
            for (int i = 0; i < 4; ++i) {
                af[i] = *(const half8*)&As[aBase + i * 16 * GP];
                bf[i] = *(const half8*)&Bs[bBase + i * 16 * GP];
            }
            #pragma unroll
            for (int i = 0; i < 4; ++i)
                #pragma unroll
                for (int j = 0; j < 4; ++j)
                    acc[i][j] = __builtin_amdgcn_mfma_f32_16x16x32_f16(af[i], bf[j], acc[i][j], 0, 0, 0);
        }
    }

    // epilogue: exclusive slice, plain stores (no atomics)
    float* D = Gpart + ((long)(ks * 8 + b) << 16);
    #pragma unroll
    for (int i = 0; i < 4; ++i)
        #pragma unroll
        for (int j = 0; j < 4; ++j) {
            const int row = r0 + wy * 64 + i * 16 + quad * 4;
            const int col = c0 + wx * 64 + j * 16 + mIn;
            #pragma unroll
            for (int r = 0; r < 4; ++r)
                D[(row + r) * 256 + col] = acc[i][j][r];
            if (tileId == 1)                        // mirrored lower-left copy
                *(float4*)&D[(long)col * 256 + row] =
                    make_float4(acc[i][j][0], acc[i][j][1], acc[i][j][2], acc[i][j][3]);
        }
}

// ---------------- K5: T1 = Wv G (reduces 8 Gpart slices in staging) + cvec += T1.w1 ----------------
__launch_bounds__(256)
__global__ void t1_kernel(const float* __restrict__ Wv, const float* __restrict__ Gpart,
                          const float* __restrict__ w1, float* __restrict__ T1,
                          float* __restrict__ cvec) {
    __shared__ float ldsA[16 * 68], ldsB[16 * 68];
    const int b = blockIdx.z;
    const int r0 = blockIdx.y * 64, j0 = blockIdx.x * 64;
    const int t = threadIdx.x, tx = t & 15, ty = t >> 4;
    const int sr = t >> 2, sk = (t & 3) * 4;
    float acc[4][4] = {};
    for (int kk = 0; kk < 256; kk += 16) {
        const float4 a4 = *(const float4*)&Wv[(long)(r0 + sr) * 256 + kk + sk];
        ldsA[(sk + 0) * 68 + sr] = a4.x;
        ldsA[(sk + 1) * 68 + sr] = a4.y;
        ldsA[(sk + 2) * 68 + sr] = a4.z;
        ldsA[(sk + 3) * 68 + sr] = a4.w;
        float4 bs = make_float4(0.f, 0.f, 0.f, 0.f);
        #pragma unroll
        for (int ksl = 0; ksl < 8; ++ksl) {        // fold splitK reduce into staging
            const float4 g = *(const float4*)&Gpart[(long)ksl * 524288 + (long)b * 65536 +
                                                    (long)(kk + ty) * 256 + j0 + tx * 4];
            bs.x += g.x; bs.y += g.y; bs.z += g.z; bs.w += g.w;
        }
        *(float4*)&ldsB[ty * 68 + tx * 4] = bs;
        __syncthreads();
        #pragma unroll
        for (int k = 0; k < 16; ++k) {
            const float4 av4 = *(const float4*)&ldsA[k * 68 + ty * 4];
            const float4 bv4 = *(const float4*)&ldsB[k * 68 + tx * 4];
            const float ar[4] = {av4.x, av4.y, av4.z, av4.w};
            const float br[4] = {bv4.x, bv4.y, bv4.z, bv4.w};
            #pragma unroll
            for (int i = 0; i < 4; ++i)
                #pragma unroll
                for (int j = 0; j < 4; ++j)
                    acc[i][j] = fmaf(ar[i], br[j], acc[i][j]);
        }
        __syncthreads();
    }
    float* D = T1 + (long)b * 65536;
    float w4[4];
    *(float4*)w4 = *(const float4*)&w1[j0 + tx * 4];
    #pragma unroll
    for (int i = 0; i < 4; ++i) {
        const int r = r0 + ty * 4 + i;
        *(float4*)&D[(long)r * 256 + j0 + tx * 4] =
            make_float4(acc[i][0], acc[i][1], acc[i][2], acc[i][3]);
        float p = acc[i][0] * w4[0] + acc[i][1] * w4[1] + acc[i][2] * w4[2] + acc[i][3] * w4[3];
        p += __shfl_xor(p, 1); p += __shfl_xor(p, 2);
        p += __shfl_xor(p, 4); p += __shfl_xor(p, 8);
        if (tx == 0) atomicAdd(&cvec[b * 256 + r], p);
    }
}

// ---------------- K6: Ap = T1 W3 + wvsx(x)u2 + bv(x)v2 -> f16 hi/lo ----------------
__launch_bounds__(256)
__global__ void ap_kernel(const float* __restrict__ T1, const float* __restrict__ W3,
                          const float* __restrict__ wvsx, const float* __restrict__ u2,
                          const float* __restrict__ bv, const float* __restrict__ v2,
                          _Float16* __restrict__ Aph, _Float16* __restrict__ Apl) {
    __shared__ float ldsA[16 * 68], ldsB[16 * 68];
    const int b = blockIdx.z;
    const int r0 = blockIdx.y * 64, j0 = blockIdx.x * 64;
    const float* A = T1 + (long)b * 65536;
    const int t = threadIdx.x, tx = t & 15, ty = t >> 4;
    const int sr = t >> 2, sk = (t & 3) * 4;
    float acc[4][4] = {};
    for (int kk = 0; kk < 256; kk += 16) {
        const float4 a4 = *(const float4*)&A[(long)(r0 + sr) * 256 + kk + sk];
        ldsA[(sk + 0) * 68 + sr] = a4.x;
        ldsA[(sk + 1) * 68 + sr] = a4.y;
        ldsA[(sk + 2) * 68 + sr] = a4.z;
        ldsA[(sk + 3) * 68 + sr] = a4.w;
        *(float4*)&ldsB[ty * 68 + tx * 4] = *(const float4*)&W3[(long)(kk + ty) * 256 + j0 + tx * 4];
        __syncthreads();
        #pragma unroll
        for (int k = 0; k < 16; ++k) {
            const float4 av4 = *(const float4*)&ldsA[k * 68 + ty * 4];
            const float4 bv4 = *(const float4*)&ldsB[k * 68 + tx * 4];
            const float ar[4] = {av4.x, av4.y, av4.z, av4.w};
            const float br[4] = {bv4.x, bv4.y, bv4.z, bv4.w};
            #pragma unroll
            for (int i = 0; i < 4; ++i)
                #pragma unroll
                for (int j = 0; j < 4; ++j)
                    acc[i][j] = fmaf(ar[i], br[j], acc[i][j]);
        }
        __syncthreads();
    }
    #pragma unroll
    for (int i = 0; i < 4; ++i) {
        const int r = r0 + ty * 4 + i;
        const float e1 = wvsx[b * 256 + r], e3 = bv[r];
        half4 hv, lv;
        #pragma unroll
        for (int j = 0; j < 4; ++j) {
            const int col = j0 + tx * 4 + j;
            const float val = acc[i][j] + e1 * u2[col] + e3 * v2[b * 256 + col];
            hv[j] = (_Float16)val;
            lv[j] = (_Float16)(val - (float)hv[j]);
        }
        const long o = (long)b * 65536 + (long)r * 256 + j0 + tx * 4;
        *(half4*)&Aph[o] = hv;
        *(half4*)&Apl[o] = lv;
    }
}

// ---------------- K7: out = (Ap x + cvec 1^T) / S  (f16-split MFMA) ----------------
__launch_bounds__(256)
__global__ void gemmF_mfma(const _Float16* __restrict__ Aph, const _Float16* __restrict__ Apl,
                           const _Float16* __restrict__ xTh, const _Float16* __restrict__ xTl,
                           const float* __restrict__ Sptr, const float* __restrict__ cvec,
                           float* __restrict__ out) {
    __shared__ __align__(16) _Float16 Ah[128 * GP];
    __shared__ __align__(16) _Float16 Al[128 * GP];
    __shared__ __align__(16) _Float16 Bh[128 * GP];
    __shared__ __align__(16) _Float16 Bl[128 * GP];

    const int n0 = blockIdx.x * 128;
    const int c0 = blockIdx.y * 128;
    const int b = blockIdx.z;
    const _Float16* Asrc_h = Aph + (long)b * 65536;
    const _Float16* Asrc_l = Apl + (long)b * 65536;
    const _Float16* Bsrc_h = xTh + (long)b * 524288;
    const _Float16* Bsrc_l = xTl + (long)b * 524288;

    const int t = threadIdx.x;
    const int lane = t & 63, wave = t >> 6;
    const int wy = wave >> 1, wx = wave & 1;
    const int mIn = lane & 15, quad = lane >> 4;

    f4v acc[4][4] = {};
    const int aBase = (wy * 64 + mIn) * GP + quad * 8;
    const int bBase = (wx * 64 + mIn) * GP + quad * 8;

    for (int kk = 0; kk < 256; kk += 32) {
        #pragma unroll
        for (int i = 0; i < 2; ++i) {
            const int idx = t + (i << 8);
            const int row = idx >> 2, ko = (idx & 3) << 3;
            *(uint4*)&Ah[row * GP + ko] = *(const uint4*)&Asrc_h[(long)(c0 + row) * 256 + kk + ko];
            *(uint4*)&Al[row * GP + ko] = *(const uint4*)&Asrc_l[(long)(c0 + row) * 256 + kk + ko];
            *(uint4*)&Bh[row * GP + ko] = *(const uint4*)&Bsrc_h[(long)(n0 + row) * 256 + kk + ko];
            *(uint4*)&Bl[row * GP + ko] = *(const uint4*)&Bsrc_l[(long)(n0 + row) * 256 + kk + ko];
        }
        __syncthreads();
        #pragma unroll
        for (int ph = 0; ph < 3; ++ph) {
            const _Float16* As = (ph == 2) ? Al : Ah;
            const _Float16* Bs = (ph == 1) ? Bl : Bh;
            half8 af[4], bf[4];
            #pragma unroll
            for (int i = 0; i < 4; ++i) {
                af[i] = *(const half8*)&As[aBase + i * 16 * GP];
                bf[i] = *(const half8*)&Bs[bBase + i * 16 * GP];
            }
            #pragma unroll
            for (int i = 0; i < 4; ++i)
                #pragma unroll
                for (int j = 0; j < 4; ++j)
                    acc[i][j] = __builtin_amdgcn_mfma_f32_16x16x32_f16(af[i], bf[j], acc[i][j], 0, 0, 0);
        }
        __syncthreads();
    }

    const float invS = 1.0f / Sptr[0];
    float* ob = out + (long)b * 524288;
    const float* cv = cvec + b * 256;
    #pragma unroll
    for (int i = 0; i < 4; ++i)
        #pragma unroll
        for (int r = 0; r < 4; ++r) {
            const int row = c0 + wy * 64 + i * 16 + quad * 4 + r;
            const float c = cv[row];
            #pragma unroll
            for (int j = 0; j < 4; ++j) {
                const int col = n0 + wx * 64 + j * 16 + mIn;
                ob[(long)row * 2048 + col] = (acc[i][j][r] + c) * invS;
            }
        }
}

extern "C" void kernel_launch(void* const* d_in, const int* in_sizes, int n_in,
                              void* d_out, int out_size, void* d_ws, size_t ws_size,
                              hipStream_t stream) {
    const float* x  = (const float*)d_in[0];
    const float* Wq = (const float*)d_in[1];
    const float* bq = (const float*)d_in[2];
    const float* Wk = (const float*)d_in[3];
    const float* bk = (const float*)d_in[4];
    const float* Wv = (const float*)d_in[5];
    const float* bv = (const float*)d_in[6];
    float* out = (float*)d_out;
    float* ws  = (float*)d_ws;

    const int B = 8;
    float* T1    = ws;                 // 524288
    float* W3    = ws + 524288;        // 65536
    float* sx    = ws + 589824;        // 2048
    float* wvsx  = ws + 591872;        // 2048
    float* v2    = ws + 593920;        // 2048
    float* cvec  = ws + 595968;        // 2048
    float* u2    = ws + 598016;        // 256
    float* w1    = ws + 598272;        // 256
    float* s1    = ws + 598528;        // 1
    float* S     = ws + 598532;        // 1
    float* Gpart = ws + 598544;        // 8*8*65536 = 4194304 floats (16 MB)
    _Float16* fh = (_Float16*)(ws + 4792848);
    _Float16* xTh = fh;                // 4194304 halves
    _Float16* xTl = fh + 4194304;
    _Float16* Aph = fh + 8388608;      // 524288 halves
    _Float16* Apl = fh + 8912896;      // total ws ~38 MB

    pre_kernel<<<dim3(3072), 256, 0, stream>>>(x, sx, S, xTh, xTl);
    prep1_kernel<<<dim3(21), 256, 0, stream>>>(Wq, Wk, Wv, bq, bk, sx, W3, u2, w1, s1, wvsx);
    prep2_kernel<<<dim3(8), 256, 0, stream>>>(W3, sx, u2, w1, s1, bv, wvsx, v2, cvec, S);
    gemmG_mfma<<<dim3(3, 64), 256, 0, stream>>>(x, Gpart);
    t1_kernel<<<dim3(4, 4, B), 256, 0, stream>>>(Wv, Gpart, w1, T1, cvec);
    ap_kernel<<<dim3(4, 4, B), 256, 0, stream>>>(T1, W3, wvsx, u2, bv, v2, Aph, Apl);
    gemmF_mfma<<<dim3(16, 2, B), 256, 0, stream>>>(Aph, Apl, xTh, xTl, S, cvec, out);
}

// Round 6
// 158.230 us; speedup vs baseline: 1.8313x; 1.1529x over previous
//
#include <hip/hip_runtime.h>

// B=8, C=256, N=2048, fp32 in/out.
// attn_b = (Ap_b x_b + cvec_b 1^T) / S
//   Ap_b = T1_b W3 + wvsx_b (x) u2 + bv (x) v2_b      (f16 hi/lo split for final MFMA)
//   T1_b = Wv G_b,  W3 = Wq^T Wk,  G_b = x_b x_b^T (symmetric)
//   u2 = Wk^T bq, w1 = Wq^T bk, s1 = bq.bk, sx_b = rowsum(x_b)
//   tq_b = Wq sx_b + N bq;  v2_b = Wk^T tq_b;  s2_b = tq_b.bk
//   S    = sum_b [ v2_b.sx_b + N s2_b ]
//   cvec_b = wvsx*s1 + bv*s2 + T1.w1   (T1.w1 via 4 exclusive tdot slices)
// 5 serial nodes: K1(pre||gemmG) -> K2(prep) -> K3(t1||prep2) -> K4(ap) -> K5(gemmF)

typedef _Float16 half8 __attribute__((ext_vector_type(8)));
typedef _Float16 half4 __attribute__((ext_vector_type(4)));
typedef float f4v __attribute__((ext_vector_type(4)));

#define GP 40   // LDS pitch (halves) for MFMA panels

// ---------------- K1: gemmG (blocks 0..191) || transpose+rowsum (192..1215) ----------------
// dynamic smem = 40960 B. gemmG: Gpart[ks*8+b] exclusive slices, pipelined loads.
// transpose: x[b][c][n] -> xTh/xTl[b][n][c] f16 hi/lo + sxpart[ntile] rowsum slices.
__launch_bounds__(256)
__global__ void pre_gemmG(const float* __restrict__ x, float* __restrict__ sxpart,
                          float* __restrict__ S, _Float16* __restrict__ xTh,
                          _Float16* __restrict__ xTl, float* __restrict__ Gpart) {
    extern __shared__ __align__(16) char smem[];
    const int blk = blockIdx.x, t = threadIdx.x;

    if (blk < 192) {
        _Float16* Ah = (_Float16*)smem;
        _Float16* Al = Ah + 128 * GP;
        _Float16* Bh = Al + 128 * GP;
        _Float16* Bl = Bh + 128 * GP;

        const int tileId = blk % 3;
        const int y = blk / 3;
        const int b  = y >> 3;
        const int ks = y & 7;
        const int r0 = (tileId == 2) ? 128 : 0;
        const int c0 = (tileId == 0) ? 0 : 128;
        const bool diag = (tileId != 1);
        const float* xb = x + (long)b * 524288;

        const int lane = t & 63, wave = t >> 6;
        const int wy = wave >> 1, wx = wave & 1;
        const int mIn = lane & 15, quad = lane >> 4;

        f4v acc[4][4] = {};
        const int aBase = (wy * 64 + mIn) * GP + quad * 8;
        const int bBase = (wx * 64 + mIn) * GP + quad * 8;
        const int srow = t >> 3;          // 0..31
        const int skq  = (t & 7) * 4;     // 0..28

        float4 pa[4], pb[4];
        int kk = ks * 256;
        #pragma unroll
        for (int i = 0; i < 4; ++i) {
            pa[i] = *(const float4*)&xb[(long)(r0 + srow + i * 32) * 2048 + kk + skq];
            if (!diag) pb[i] = *(const float4*)&xb[(long)(c0 + srow + i * 32) * 2048 + kk + skq];
        }

        for (int kb = 0; kb < 8; ++kb) {
            if (kb) __syncthreads();
            #pragma unroll
            for (int i = 0; i < 4; ++i) {
                const int row = srow + i * 32;
                half4 hv, lv;
                hv[0] = (_Float16)pa[i].x; lv[0] = (_Float16)(pa[i].x - (float)hv[0]);
                hv[1] = (_Float16)pa[i].y; lv[1] = (_Float16)(pa[i].y - (float)hv[1]);
                hv[2] = (_Float16)pa[i].z; lv[2] = (_Float16)(pa[i].z - (float)hv[2]);
                hv[3] = (_Float16)pa[i].w; lv[3] = (_Float16)(pa[i].w - (float)hv[3]);
                *(half4*)&Ah[row * GP + skq] = hv;
                *(half4*)&Al[row * GP + skq] = lv;
                if (!diag) {
                    half4 hb, lb;
                    hb[0] = (_Float16)pb[i].x; lb[0] = (_Float16)(pb[i].x - (float)hb[0]);
                    hb[1] = (_Float16)pb[i].y; lb[1] = (_Float16)(pb[i].y - (float)hb[1]);
                    hb[2] = (_Float16)pb[i].z; lb[2] = (_Float16)(pb[i].z - (float)hb[2]);
                    hb[3] = (_Float16)pb[i].w; lb[3] = (_Float16)(pb[i].w - (float)hb[3]);
                    *(half4*)&Bh[row * GP + skq] = hb;
                    *(half4*)&Bl[row * GP + skq] = lb;
                }
            }
            __syncthreads();
            kk += 32;
            if (kb < 7) {
                #pragma unroll
                for (int i = 0; i < 4; ++i) {
                    pa[i] = *(const float4*)&xb[(long)(r0 + srow + i * 32) * 2048 + kk + skq];
                    if (!diag) pb[i] = *(const float4*)&xb[(long)(c0 + srow + i * 32) * 2048 + kk + skq];
                }
            }
            const _Float16* BhP = diag ? Ah : Bh;
            const _Float16* BlP = diag ? Al : Bl;
            #pragma unroll
            for (int ph = 0; ph < 3; ++ph) {
                const _Float16* As = (ph == 2) ? Al : Ah;
                const _Float16* Bs = (ph == 1) ? BlP : BhP;
                half8 af[4], bf[4];
                #pragma unroll
                for (int i = 0; i < 4; ++i) {
                    af[i] = *(const half8*)&As[aBase + i * 16 * GP];
                    bf[i] = *(const half8*)&Bs[bBase + i * 16 * GP];
                }
                #pragma unroll
                for (int i = 0; i < 4; ++i)
                    #pragma unroll
                    for (int j = 0; j < 4; ++j)
                        acc[i][j] = __builtin_amdgcn_mfma_f32_16x16x32_f16(af[i], bf[j], acc[i][j], 0, 0, 0);
            }
        }

        float* D = Gpart + ((long)(ks * 8 + b) << 16);
        #pragma unroll
        for (int i = 0; i < 4; ++i)
            #pragma unroll
            for (int j = 0; j < 4; ++j) {
                const int row = r0 + wy * 64 + i * 16 + quad * 4;
                const int col = c0 + wx * 64 + j * 16 + mIn;
                #pragma unroll
                for (int r = 0; r < 4; ++r)
                    D[(row + r) * 256 + col] = acc[i][j][r];
                if (tileId == 1)
                    *(float4*)&D[(long)col * 256 + row] =
                        make_float4(acc[i][j][0], acc[i][j][1], acc[i][j][2], acc[i][j][3]);
            }
    } else {
        if (blk == 192 && t == 0) S[0] = 0.0f;
        float* tl  = (float*)smem;            // [64][65]
        float* red = (float*)(smem + 16640);  // [256]
        const int tile = blk - 192;           // 0..1023
        const int b  = tile >> 7;
        const int tb = tile & 127;
        const int ntile = tb & 31;
        const int n0 = ntile * 64;
        const int c0 = (tb >> 5) * 64;
        const float* xb = x + (long)b * 524288;
        #pragma unroll
        for (int p = 0; p < 16; ++p) {
            const int idx = t + p * 256;
            const int r = idx >> 6, c = idx & 63;
            tl[r * 65 + c] = xb[(long)(c0 + r) * 2048 + n0 + c];
        }
        __syncthreads();
        #pragma unroll
        for (int p = 0; p < 16; ++p) {
            const int idx = t + p * 256;
            const int n = idx >> 6, c = idx & 63;
            const float v = tl[c * 65 + n];
            const _Float16 h = (_Float16)v;
            const _Float16 l = (_Float16)(v - (float)h);
            const long o = (long)b * 524288 + (long)(n0 + n) * 256 + c0 + c;
            xTh[o] = h; xTl[o] = l;
        }
        // rowsum partial over this tile's 64 n-values per channel
        const int c = t & 63, q = t >> 6;
        float s = 0.0f;
        #pragma unroll
        for (int k = 0; k < 16; ++k) s += tl[c * 65 + q * 16 + k];
        red[t] = s; __syncthreads();
        if (t < 64)
            sxpart[ntile * 2048 + b * 256 + c0 + t] =
                red[t] + red[t + 64] + red[t + 128] + red[t + 192];
    }
}

// ---------------- K2: W3 (0..15) | u2,w1,s1 (16) | wvsx (17..20) | tq (21..24) ----------------
__launch_bounds__(256)
__global__ void prep1_kernel(const float* __restrict__ Wq, const float* __restrict__ Wk,
                             const float* __restrict__ Wv, const float* __restrict__ bq,
                             const float* __restrict__ bk, const float* __restrict__ sxpart,
                             float* __restrict__ W3, float* __restrict__ u2,
                             float* __restrict__ w1, float* __restrict__ s1,
                             float* __restrict__ wvsx, float* __restrict__ tq) {
    const int blk = blockIdx.x, t = threadIdx.x;
    if (blk < 16) {
        const int r0 = (blk >> 2) * 64, j0 = (blk & 3) * 64;
        __shared__ float ldsA[16 * 68], ldsB[16 * 68];
        const int tx = t & 15, ty = t >> 4;
        float acc[4][4] = {};
        for (int kk = 0; kk < 256; kk += 16) {
            *(float4*)&ldsA[ty * 68 + tx * 4] = *(const float4*)&Wq[(long)(kk + ty) * 256 + r0 + tx * 4];
            *(float4*)&ldsB[ty * 68 + tx * 4] = *(const float4*)&Wk[(long)(kk + ty) * 256 + j0 + tx * 4];
            __syncthreads();
            #pragma unroll
            for (int k = 0; k < 16; ++k) {
                const float4 av4 = *(const float4*)&ldsA[k * 68 + ty * 4];
                const float4 bv4 = *(const float4*)&ldsB[k * 68 + tx * 4];
                const float ar[4] = {av4.x, av4.y, av4.z, av4.w};
                const float br[4] = {bv4.x, bv4.y, bv4.z, bv4.w};
                #pragma unroll
                for (int i = 0; i < 4; ++i)
                    #pragma unroll
                    for (int j = 0; j < 4; ++j)
                        acc[i][j] = fmaf(ar[i], br[j], acc[i][j]);
            }
            __syncthreads();
        }
        #pragma unroll
        for (int i = 0; i < 4; ++i)
            *(float4*)&W3[(long)(r0 + ty * 4 + i) * 256 + j0 + tx * 4] =
                make_float4(acc[i][0], acc[i][1], acc[i][2], acc[i][3]);
    } else if (blk == 16) {
        __shared__ float sbq[256], sbk[256], red[256];
        sbq[t] = bq[t]; sbk[t] = bk[t];
        __syncthreads();
        float u = 0.0f, w = 0.0f;
        #pragma unroll 8
        for (int c = 0; c < 256; ++c) {
            u = fmaf(Wk[(long)c * 256 + t], sbq[c], u);
            w = fmaf(Wq[(long)c * 256 + t], sbk[c], w);
        }
        u2[t] = u; w1[t] = w;
        red[t] = sbq[t] * sbk[t]; __syncthreads();
        for (int h = 128; h > 0; h >>= 1) { if (t < h) red[t] += red[t + h]; __syncthreads(); }
        if (t == 0) s1[0] = red[0];
    } else {
        // skinny GEMM: out[b, r0w+r] = sum_c M[r0w+r, c] * sx[b, c]  (+ N*bias)
        const int sel = blk - 17;                       // 0..7
        const bool isTq = sel >= 4;
        const float* M = isTq ? Wq : Wv;
        const int r0w = (sel & 3) * 64;
        __shared__ float wtile[64 * 256];
        __shared__ float sxs[2048];
        #pragma unroll
        for (int p = 0; p < 16; ++p) {
            const int idx = t + p * 256;
            const int row = idx >> 6, f4 = idx & 63;
            *(float4*)&wtile[row * 256 + f4 * 4] = *(const float4*)&M[(long)(r0w + row) * 256 + f4 * 4];
        }
        #pragma unroll
        for (int p = 0; p < 8; ++p) {
            const int idx = t + p * 256;
            float s = 0.0f;
            for (int nt = 0; nt < 32; ++nt) s += sxpart[nt * 2048 + idx];
            sxs[idx] = s;
        }
        __syncthreads();
        const int r = t >> 2, q = t & 3;
        float acc[8] = {};
        for (int ci = 0; ci < 64; ++ci) {
            const float wv = wtile[r * 256 + q * 64 + ci];
            #pragma unroll
            for (int b = 0; b < 8; ++b) acc[b] = fmaf(wv, sxs[b * 256 + q * 64 + ci], acc[b]);
        }
        #pragma unroll
        for (int b = 0; b < 8; ++b) {
            acc[b] += __shfl_xor(acc[b], 1);
            acc[b] += __shfl_xor(acc[b], 2);
        }
        if (q == 0) {
            if (isTq) {
                const float bias = 2048.0f * bq[r0w + r];
                #pragma unroll
                for (int b = 0; b < 8; ++b) tq[b * 256 + r0w + r] = acc[b] + bias;
            } else {
                #pragma unroll
                for (int b = 0; b < 8; ++b) wvsx[b * 256 + r0w + r] = acc[b];
            }
        }
    }
}

// ---------------- K3: t1 gemm (0..127) || prep2 (128..135) ----------------
// gemm: T1 = Wv * (sum_ks Gpart) ; tdot[j0slice][b,r] = partial T1.w1 (plain stores)
// prep2: v2 = Wk^T tq; S += v2.sx + N tq.bk; cvecInit = wvsx*s1 + bv*(tq.bk)
__launch_bounds__(256)
__global__ void t1_kernel(const float* __restrict__ Wv, const float* __restrict__ Gpart,
                          const float* __restrict__ Wk, const float* __restrict__ bk,
                          const float* __restrict__ bv, const float* __restrict__ tq,
                          const float* __restrict__ sxpart, const float* __restrict__ s1p,
                          const float* __restrict__ wvsx, const float* __restrict__ w1,
                          float* __restrict__ T1, float* __restrict__ tdot,
                          float* __restrict__ v2, float* __restrict__ cvecInit,
                          float* __restrict__ S) {
    const int blk = blockIdx.x, t = threadIdx.x;
    if (blk < 128) {
        __shared__ float ldsA[16 * 68], ldsB[16 * 68];
        const int j0s = blk & 3;
        const int j0 = j0s * 64;
        const int r0 = ((blk >> 2) & 3) * 64;
        const int b = blk >> 4;
        const int tx = t & 15, ty = t >> 4;
        const int sr = t >> 2, sk = (t & 3) * 4;
        float acc[4][4] = {};
        for (int kk = 0; kk < 256; kk += 16) {
            const float4 a4 = *(const float4*)&Wv[(long)(r0 + sr) * 256 + kk + sk];
            ldsA[(sk + 0) * 68 + sr] = a4.x;
            ldsA[(sk + 1) * 68 + sr] = a4.y;
            ldsA[(sk + 2) * 68 + sr] = a4.z;
            ldsA[(sk + 3) * 68 + sr] = a4.w;
            float4 bs = make_float4(0.f, 0.f, 0.f, 0.f);
            #pragma unroll
            for (int ksl = 0; ksl < 8; ++ksl) {
                const float4 g = *(const float4*)&Gpart[(long)ksl * 524288 + (long)b * 65536 +
                                                        (long)(kk + ty) * 256 + j0 + tx * 4];
                bs.x += g.x; bs.y += g.y; bs.z += g.z; bs.w += g.w;
            }
            *(float4*)&ldsB[ty * 68 + tx * 4] = bs;
            __syncthreads();
            #pragma unroll
            for (int k = 0; k < 16; ++k) {
                const float4 av4 = *(const float4*)&ldsA[k * 68 + ty * 4];
                const float4 bv4 = *(const float4*)&ldsB[k * 68 + tx * 4];
                const float ar[4] = {av4.x, av4.y, av4.z, av4.w};
                const float br[4] = {bv4.x, bv4.y, bv4.z, bv4.w};
                #pragma unroll
                for (int i = 0; i < 4; ++i)
                    #pragma unroll
                    for (int j = 0; j < 4; ++j)
                        acc[i][j] = fmaf(ar[i], br[j], acc[i][j]);
            }
            __syncthreads();
        }
        float* D = T1 + (long)b * 65536;
        float w4[4];
        *(float4*)w4 = *(const float4*)&w1[j0 + tx * 4];
        #pragma unroll
        for (int i = 0; i < 4; ++i) {
            const int r = r0 + ty * 4 + i;
            *(float4*)&D[(long)r * 256 + j0 + tx * 4] =
                make_float4(acc[i][0], acc[i][1], acc[i][2], acc[i][3]);
            float p = acc[i][0] * w4[0] + acc[i][1] * w4[1] + acc[i][2] * w4[2] + acc[i][3] * w4[3];
            p += __shfl_xor(p, 1); p += __shfl_xor(p, 2);
            p += __shfl_xor(p, 4); p += __shfl_xor(p, 8);
            if (tx == 0) tdot[j0s * 2048 + b * 256 + r] = p;
        }
    } else {
        const int b = blk - 128, j = t;
        __shared__ float ssx[256], stq[256], red[256];
        float s = 0.0f;
        for (int nt = 0; nt < 32; ++nt) s += sxpart[nt * 2048 + b * 256 + j];
        ssx[j] = s;
        stq[j] = tq[b * 256 + j];
        __syncthreads();
        float vr = 0.0f;
        #pragma unroll 8
        for (int c = 0; c < 256; ++c) vr = fmaf(Wk[(long)c * 256 + j], stq[c], vr);  // coalesced
        v2[b * 256 + j] = vr;
        __shared__ float sd1;
        red[j] = vr * ssx[j]; __syncthreads();
        for (int h = 128; h > 0; h >>= 1) { if (j < h) red[j] += red[j + h]; __syncthreads(); }
        if (j == 0) sd1 = red[0];
        __syncthreads();
        red[j] = stq[j] * bk[j]; __syncthreads();
        for (int h = 128; h > 0; h >>= 1) { if (j < h) red[j] += red[j + h]; __syncthreads(); }
        const float s2v = red[0];
        if (j == 0) atomicAdd(S, sd1 + 2048.0f * s2v);
        cvecInit[b * 256 + j] = wvsx[b * 256 + j] * s1p[0] + bv[j] * s2v;
    }
}

// ---------------- K4: Ap = T1 W3 + wvsx(x)u2 + bv(x)v2 -> f16 hi/lo ----------------
__launch_bounds__(256)
__global__ void ap_kernel(const float* __restrict__ T1, const float* __restrict__ W3,
                          const float* __restrict__ wvsx, const float* __restrict__ u2,
                          const float* __restrict__ bv, const float* __restrict__ v2,
                          _Float16* __restrict__ Aph, _Float16* __restrict__ Apl) {
    __shared__ float ldsA[16 * 68], ldsB[16 * 68];
    const int b = blockIdx.z;
    const int r0 = blockIdx.y * 64, j0 = blockIdx.x * 64;
    const float* A = T1 + (long)b * 65536;
    const int t = threadIdx.x, tx = t & 15, ty = t >> 4;
    const int sr = t >> 2, sk = (t & 3) * 4;
    float acc[4][4] = {};
    for (int kk = 0; kk < 256; kk += 16) {
        const float4 a4 = *(const float4*)&A[(long)(r0 + sr) * 256 + kk + sk];
        ldsA[(sk + 0) * 68 + sr] = a4.x;
        ldsA[(sk + 1) * 68 + sr] = a4.y;
        ldsA[(sk + 2) * 68 + sr] = a4.z;
        ldsA[(sk + 3) * 68 + sr] = a4.w;
        *(float4*)&ldsB[ty * 68 + tx * 4] = *(const float4*)&W3[(long)(kk + ty) * 256 + j0 + tx * 4];
        __syncthreads();
        #pragma unroll
        for (int k = 0; k < 16; ++k) {
            const float4 av4 = *(const float4*)&ldsA[k * 68 + ty * 4];
            const float4 bv4 = *(const float4*)&ldsB[k * 68 + tx * 4];
            const float ar[4] = {av4.x, av4.y, av4.z, av4.w};
            const float br[4] = {bv4.x, bv4.y, bv4.z, bv4.w};
            #pragma unroll
            for (int i = 0; i < 4; ++i)
                #pragma unroll
                for (int j = 0; j < 4; ++j)
                    acc[i][j] = fmaf(ar[i], br[j], acc[i][j]);
        }
        __syncthreads();
    }
    #pragma unroll
    for (int i = 0; i < 4; ++i) {
        const int r = r0 + ty * 4 + i;
        const float e1 = wvsx[b * 256 + r], e3 = bv[r];
        half4 hv, lv;
        #pragma unroll
        for (int j = 0; j < 4; ++j) {
            const int col = j0 + tx * 4 + j;
            const float val = acc[i][j] + e1 * u2[col] + e3 * v2[b * 256 + col];
            hv[j] = (_Float16)val;
            lv[j] = (_Float16)(val - (float)hv[j]);
        }
        const long o = (long)b * 65536 + (long)r * 256 + j0 + tx * 4;
        *(half4*)&Aph[o] = hv;
        *(half4*)&Apl[o] = lv;
    }
}

// ---------------- K5: out = (Ap x + cvec 1^T) / S  (f16-split MFMA) ----------------
__launch_bounds__(256)
__global__ void gemmF_mfma(const _Float16* __restrict__ Aph, const _Float16* __restrict__ Apl,
                           const _Float16* __restrict__ xTh, const _Float16* __restrict__ xTl,
                           const float* __restrict__ Sptr, const float* __restrict__ cvecInit,
                           const float* __restrict__ tdot, float* __restrict__ out) {
    __shared__ __align__(16) _Float16 Ah[128 * GP];
    __shared__ __align__(16) _Float16 Al[128 * GP];
    __shared__ __align__(16) _Float16 Bh[128 * GP];
    __shared__ __align__(16) _Float16 Bl[128 * GP];

    const int n0 = blockIdx.x * 128;
    const int c0 = blockIdx.y * 128;
    const int b = blockIdx.z;
    const _Float16* Asrc_h = Aph + (long)b * 65536;
    const _Float16* Asrc_l = Apl + (long)b * 65536;
    const _Float16* Bsrc_h = xTh + (long)b * 524288;
    const _Float16* Bsrc_l = xTl + (long)b * 524288;

    const int t = threadIdx.x;
    const int lane = t & 63, wave = t >> 6;
    const int wy = wave >> 1, wx = wave & 1;
    const int mIn = lane & 15, quad = lane >> 4;

    f4v acc[4][4] = {};
    const int aBase = (wy * 64 + mIn) * GP + quad * 8;
    const int bBase = (wx * 64 + mIn) * GP + quad * 8;

    for (int kk = 0; kk < 256; kk += 32) {
        #pragma unroll
        for (int i = 0; i < 2; ++i) {
            const int idx = t + (i << 8);
            const int row = idx >> 2, ko = (idx & 3) << 3;
            *(uint4*)&Ah[row * GP + ko] = *(const uint4*)&Asrc_h[(long)(c0 + row) * 256 + kk + ko];
            *(uint4*)&Al[row * GP + ko] = *(const uint4*)&Asrc_l[(long)(c0 + row) * 256 + kk + ko];
            *(uint4*)&Bh[row * GP + ko] = *(const uint4*)&Bsrc_h[(long)(n0 + row) * 256 + kk + ko];
            *(uint4*)&Bl[row * GP + ko] = *(const uint4*)&Bsrc_l[(long)(n0 + row) * 256 + kk + ko];
        }
        __syncthreads();
        #pragma unroll
        for (int ph = 0; ph < 3; ++ph) {
            const _Float16* As = (ph == 2) ? Al : Ah;
            const _Float16* Bs = (ph == 1) ? Bl : Bh;
            half8 af[4], bf[4];
            #pragma unroll
            for (int i = 0; i < 4; ++i) {
                af[i] = *(const half8*)&As[aBase + i * 16 * GP];
                bf[i] = *(const half8*)&Bs[bBase + i * 16 * GP];
            }
            #pragma unroll
            for (int i = 0; i < 4; ++i)
                #pragma unroll
                for (int j = 0; j < 4; ++j)
                    acc[i][j] = __builtin_amdgcn_mfma_f32_16x16x32_f16(af[i], bf[j], acc[i][j], 0, 0, 0);
        }
        __syncthreads();
    }

    const float invS = 1.0f / Sptr[0];
    float* ob = out + (long)b * 524288;
    #pragma unroll
    for (int i = 0; i < 4; ++i)
        #pragma unroll
        for (int r = 0; r < 4; ++r) {
            const int row = c0 + wy * 64 + i * 16 + quad * 4 + r;
            const int ci = b * 256 + row;
            const float c = cvecInit[ci] + tdot[ci] + tdot[2048 + ci] +
                            tdot[4096 + ci] + tdot[6144 + ci];
            #pragma unroll
            for (int j = 0; j < 4; ++j) {
                const int col = n0 + wx * 64 + j * 16 + mIn;
                ob[(long)row * 2048 + col] = (acc[i][j][r] + c) * invS;
            }
        }
}

extern "C" void kernel_launch(void* const* d_in, const int* in_sizes, int n_in,
                              void* d_out, int out_size, void* d_ws, size_t ws_size,
                              hipStream_t stream) {
    const float* x  = (const float*)d_in[0];
    const float* Wq = (const float*)d_in[1];
    const float* bq = (const float*)d_in[2];
    const float* Wk = (const float*)d_in[3];
    const float* bk = (const float*)d_in[4];
    const float* Wv = (const float*)d_in[5];
    const float* bv = (const float*)d_in[6];
    float* out = (float*)d_out;
    float* ws  = (float*)d_ws;

    const int B = 8;
    float* T1     = ws;                 // 524288
    float* W3     = ws + 524288;        // 65536
    float* sxpart = ws + 589824;        // 32*2048 = 65536
    float* wvsx   = ws + 655360;        // 2048
    float* v2     = ws + 657408;        // 2048
    float* cvecI  = ws + 659456;        // 2048
    float* tq     = ws + 661504;        // 2048
    float* tdot   = ws + 663552;        // 4*2048 = 8192
    float* u2     = ws + 671744;        // 256
    float* w1     = ws + 672000;        // 256
    float* s1     = ws + 672256;        // 1
    float* S      = ws + 672260;        // 1
    float* Gpart  = ws + 672288;        // 8*8*65536 = 4194304 (16 MB)
    _Float16* fh  = (_Float16*)(ws + 4866592);
    _Float16* xTh = fh;                 // 4194304 halves
    _Float16* xTl = fh + 4194304;
    _Float16* Aph = fh + 8388608;       // 524288 halves
    _Float16* Apl = fh + 8912896;       // total ws ~38.3 MB

    pre_gemmG<<<dim3(1216), 256, 40960, stream>>>(x, sxpart, S, xTh, xTl, Gpart);
    prep1_kernel<<<dim3(25), 256, 0, stream>>>(Wq, Wk, Wv, bq, bk, sxpart,
                                               W3, u2, w1, s1, wvsx, tq);
    t1_kernel<<<dim3(136), 256, 0, stream>>>(Wv, Gpart, Wk, bk, bv, tq, sxpart, s1,
                                             wvsx, w1, T1, tdot, v2, cvecI, S);
    ap_kernel<<<dim3(4, 4, B), 256, 0, stream>>>(T1, W3, wvsx, u2, bv, v2, Aph, Apl);
    gemmF_mfma<<<dim3(16, 2, B), 256, 0, stream>>>(Aph, Apl, xTh, xTl, S, cvecI, tdot, out);
}

// Round 7
// 155.465 us; speedup vs baseline: 1.8639x; 1.0178x over previous
//
#include <hip/hip_runtime.h>

// B=8, C=256, N=2048, fp32 in/out.
// attn_b = (Ap_b x_b + cvec_b 1^T) / S
//   Ap_b = T1_b W3 + wvsx_b (x) u2 + bv (x) v2_b      (f16 hi/lo split MFMA)
//   T1_b = Wv G_b,  W3 = Wq^T Wk,  G_b = x_b x_b^T (symmetric)
//   u2 = Wk^T bq, w1 = Wq^T bk, s1 = bq.bk, sx_b = rowsum(x_b)
//   v2_b = W3^T sx_b + N u2;  s2_b = sx.w1 + N s1;  S = sum_b [v2.sx + N s2]
//   cvec_b = T1.w1 + wvsx*s1 + bv*s2    (computed inside ap)
// 4 serial nodes: K1(gemmG+rowsum || W3 || u2w1s1) -> K2(t1 || prep2 || wvsx)
//                 -> K3(ap + cvec) -> K4(gemmF, in-kernel x transpose-convert)

typedef _Float16 half8 __attribute__((ext_vector_type(8)));
typedef _Float16 half4 __attribute__((ext_vector_type(4)));
typedef _Float16 half2v __attribute__((ext_vector_type(2)));
typedef float f4v __attribute__((ext_vector_type(4)));

#define GP  40   // LDS pitch (halves), A panels / gemmG (16B-aligned rows)
#define GPB 36   // gemmF B panel pitch: 18-dword row stride -> 2-way (free) banking

// ---------------- K1: gemmG splitK=4 (+rowsum) | W3 | u2/w1/s1 ----------------
// blocks 0..95: gemmG; 96..111: W3 tiles; 112: u2/w1/s1 + zero S.
__launch_bounds__(256)
__global__ void k1_kernel(const float* __restrict__ x, const float* __restrict__ Wq,
                          const float* __restrict__ Wk, const float* __restrict__ bq,
                          const float* __restrict__ bk, float* __restrict__ sxpart,
                          float* __restrict__ W3, float* __restrict__ u2,
                          float* __restrict__ w1, float* __restrict__ s1,
                          float* __restrict__ S, float* __restrict__ Gpart) {
    __shared__ __align__(16) char smem[40960];
    const int blk = blockIdx.x, t = threadIdx.x;
    if (blk < 96) {
        _Float16* Ah = (_Float16*)smem;
        _Float16* Al = Ah + 128 * GP;
        _Float16* Bh = Al + 128 * GP;
        _Float16* Bl = Bh + 128 * GP;
        const int tileId = blk % 3;
        const int y = blk / 3;                 // 0..31
        const int b = y >> 2, ks = y & 3;
        const int r0 = (tileId == 2) ? 128 : 0;
        const int c0 = (tileId == 0) ? 0 : 128;
        const bool diag = (tileId != 1);
        const float* xb = x + (long)b * 524288;

        const int lane = t & 63, wave = t >> 6;
        const int wy = wave >> 1, wx = wave & 1;
        const int mIn = lane & 15, quad = lane >> 4;

        f4v acc[4][4] = {};
        const int aBase = (wy * 64 + mIn) * GP + quad * 8;
        const int bBase = (wx * 64 + mIn) * GP + quad * 8;
        const int srow = t >> 3;               // 0..31
        const int skq  = (t & 7) * 4;          // 0..28
        float rs[4] = {};                      // rowsum partials (diag only)

        float4 pa[4], pb[4];
        int kk = ks * 512;
        #pragma unroll
        for (int i = 0; i < 4; ++i) {
            pa[i] = *(const float4*)&xb[(long)(r0 + srow + i * 32) * 2048 + kk + skq];
            if (!diag) pb[i] = *(const float4*)&xb[(long)(c0 + srow + i * 32) * 2048 + kk + skq];
        }

        for (int kb = 0; kb < 16; ++kb) {
            if (kb) __syncthreads();
            #pragma unroll
            for (int i = 0; i < 4; ++i) {
                const int row = srow + i * 32;
                half4 hv, lv;
                hv[0] = (_Float16)pa[i].x; lv[0] = (_Float16)(pa[i].x - (float)hv[0]);
                hv[1] = (_Float16)pa[i].y; lv[1] = (_Float16)(pa[i].y - (float)hv[1]);
                hv[2] = (_Float16)pa[i].z; lv[2] = (_Float16)(pa[i].z - (float)hv[2]);
                hv[3] = (_Float16)pa[i].w; lv[3] = (_Float16)(pa[i].w - (float)hv[3]);
                *(half4*)&Ah[row * GP + skq] = hv;
                *(half4*)&Al[row * GP + skq] = lv;
                if (diag) {
                    rs[i] += pa[i].x + pa[i].y + pa[i].z + pa[i].w;
                } else {
                    half4 hb, lb;
                    hb[0] = (_Float16)pb[i].x; lb[0] = (_Float16)(pb[i].x - (float)hb[0]);
                    hb[1] = (_Float16)pb[i].y; lb[1] = (_Float16)(pb[i].y - (float)hb[1]);
                    hb[2] = (_Float16)pb[i].z; lb[2] = (_Float16)(pb[i].z - (float)hb[2]);
                    hb[3] = (_Float16)pb[i].w; lb[3] = (_Float16)(pb[i].w - (float)hb[3]);
                    *(half4*)&Bh[row * GP + skq] = hb;
                    *(half4*)&Bl[row * GP + skq] = lb;
                }
            }
            __syncthreads();
            kk += 32;
            if (kb < 15) {
                #pragma unroll
                for (int i = 0; i < 4; ++i) {
                    pa[i] = *(const float4*)&xb[(long)(r0 + srow + i * 32) * 2048 + kk + skq];
                    if (!diag) pb[i] = *(const float4*)&xb[(long)(c0 + srow + i * 32) * 2048 + kk + skq];
                }
            }
            const _Float16* BhP = diag ? Ah : Bh;
            const _Float16* BlP = diag ? Al : Bl;
            #pragma unroll
            for (int ph = 0; ph < 3; ++ph) {
                const _Float16* As = (ph == 2) ? Al : Ah;
                const _Float16* Bs = (ph == 1) ? BlP : BhP;
                half8 af[4], bf[4];
                #pragma unroll
                for (int i = 0; i < 4; ++i) {
                    af[i] = *(const half8*)&As[aBase + i * 16 * GP];
                    bf[i] = *(const half8*)&Bs[bBase + i * 16 * GP];
                }
                #pragma unroll
                for (int i = 0; i < 4; ++i)
                    #pragma unroll
                    for (int j = 0; j < 4; ++j)
                        acc[i][j] = __builtin_amdgcn_mfma_f32_16x16x32_f16(af[i], bf[j], acc[i][j], 0, 0, 0);
            }
        }

        if (diag) {
            #pragma unroll
            for (int i = 0; i < 4; ++i) {
                rs[i] += __shfl_xor(rs[i], 1);
                rs[i] += __shfl_xor(rs[i], 2);
                rs[i] += __shfl_xor(rs[i], 4);
            }
            if ((t & 7) == 0) {
                #pragma unroll
                for (int i = 0; i < 4; ++i)
                    sxpart[ks * 2048 + b * 256 + r0 + srow + i * 32] = rs[i];
            }
        }

        float* D = Gpart + ((long)(ks * 8 + b) << 16);
        #pragma unroll
        for (int i = 0; i < 4; ++i)
            #pragma unroll
            for (int j = 0; j < 4; ++j) {
                const int row = r0 + wy * 64 + i * 16 + quad * 4;
                const int col = c0 + wx * 64 + j * 16 + mIn;
                #pragma unroll
                for (int r = 0; r < 4; ++r)
                    D[(row + r) * 256 + col] = acc[i][j][r];
                if (tileId == 1)
                    *(float4*)&D[(long)col * 256 + row] =
                        make_float4(acc[i][j][0], acc[i][j][1], acc[i][j][2], acc[i][j][3]);
            }
    } else if (blk < 112) {
        float* ldsA = (float*)smem;
        float* ldsB = ldsA + 16 * 68;
        const int tile = blk - 96;
        const int r0 = (tile >> 2) * 64, j0 = (tile & 3) * 64;
        const int tx = t & 15, ty = t >> 4;
        float acc[4][4] = {};
        for (int kk = 0; kk < 256; kk += 16) {
            *(float4*)&ldsA[ty * 68 + tx * 4] = *(const float4*)&Wq[(long)(kk + ty) * 256 + r0 + tx * 4];
            *(float4*)&ldsB[ty * 68 + tx * 4] = *(const float4*)&Wk[(long)(kk + ty) * 256 + j0 + tx * 4];
            __syncthreads();
            #pragma unroll
            for (int k = 0; k < 16; ++k) {
                const float4 av4 = *(const float4*)&ldsA[k * 68 + ty * 4];
                const float4 bv4 = *(const float4*)&ldsB[k * 68 + tx * 4];
                const float ar[4] = {av4.x, av4.y, av4.z, av4.w};
                const float br[4] = {bv4.x, bv4.y, bv4.z, bv4.w};
                #pragma unroll
                for (int i = 0; i < 4; ++i)
                    #pragma unroll
                    for (int j = 0; j < 4; ++j)
                        acc[i][j] = fmaf(ar[i], br[j], acc[i][j]);
            }
            __syncthreads();
        }
        #pragma unroll
        for (int i = 0; i < 4; ++i)
            *(float4*)&W3[(long)(r0 + ty * 4 + i) * 256 + j0 + tx * 4] =
                make_float4(acc[i][0], acc[i][1], acc[i][2], acc[i][3]);
    } else {
        float* sbq = (float*)smem;
        float* sbk = sbq + 256;
        float* red = sbk + 256;
        if (t == 0) S[0] = 0.0f;
        sbq[t] = bq[t]; sbk[t] = bk[t];
        __syncthreads();
        float u = 0.0f, w = 0.0f;
        #pragma unroll 8
        for (int c = 0; c < 256; ++c) {
            u = fmaf(Wk[(long)c * 256 + t], sbq[c], u);   // coalesced columns
            w = fmaf(Wq[(long)c * 256 + t], sbk[c], w);
        }
        u2[t] = u; w1[t] = w;
        red[t] = sbq[t] * sbk[t]; __syncthreads();
        for (int h = 128; h > 0; h >>= 1) { if (t < h) red[t] += red[t + h]; __syncthreads(); }
        if (t == 0) s1[0] = red[0];
    }
}

// ---------------- K2: t1 (0..127) | prep2 (128..135) | wvsx (136..143) ----------------
__launch_bounds__(256)
__global__ void k2_kernel(const float* __restrict__ Wv, const float* __restrict__ Gpart,
                          const float* __restrict__ W3, const float* __restrict__ u2,
                          const float* __restrict__ w1, const float* __restrict__ s1p,
                          const float* __restrict__ sxpart, float* __restrict__ T1,
                          float* __restrict__ v2, float* __restrict__ s2,
                          float* __restrict__ wvsx, float* __restrict__ S) {
    __shared__ __align__(16) char smem[40960];
    const int blk = blockIdx.x, t = threadIdx.x;
    if (blk < 128) {
        float* ldsA = (float*)smem;
        float* ldsB = ldsA + 16 * 68;
        const int j0 = (blk & 3) * 64;
        const int r0 = ((blk >> 2) & 3) * 64;
        const int b = blk >> 4;
        const int tx = t & 15, ty = t >> 4;
        const int sr = t >> 2, sk = (t & 3) * 4;
        float acc[4][4] = {};
        for (int kk = 0; kk < 256; kk += 16) {
            const float4 a4 = *(const float4*)&Wv[(long)(r0 + sr) * 256 + kk + sk];
            ldsA[(sk + 0) * 68 + sr] = a4.x;
            ldsA[(sk + 1) * 68 + sr] = a4.y;
            ldsA[(sk + 2) * 68 + sr] = a4.z;
            ldsA[(sk + 3) * 68 + sr] = a4.w;
            float4 bs = make_float4(0.f, 0.f, 0.f, 0.f);
            #pragma unroll
            for (int ksl = 0; ksl < 4; ++ksl) {         // fold splitK reduce into staging
                const float4 g = *(const float4*)&Gpart[(long)ksl * 524288 + (long)b * 65536 +
                                                        (long)(kk + ty) * 256 + j0 + tx * 4];
                bs.x += g.x; bs.y += g.y; bs.z += g.z; bs.w += g.w;
            }
            *(float4*)&ldsB[ty * 68 + tx * 4] = bs;
            __syncthreads();
            #pragma unroll
            for (int k = 0; k < 16; ++k) {
                const float4 av4 = *(const float4*)&ldsA[k * 68 + ty * 4];
                const float4 bv4 = *(const float4*)&ldsB[k * 68 + tx * 4];
                const float ar[4] = {av4.x, av4.y, av4.z, av4.w};
                const float br[4] = {bv4.x, bv4.y, bv4.z, bv4.w};
                #pragma unroll
                for (int i = 0; i < 4; ++i)
                    #pragma unroll
                    for (int j = 0; j < 4; ++j)
                        acc[i][j] = fmaf(ar[i], br[j], acc[i][j]);
            }
            __syncthreads();
        }
        float* D = T1 + (long)b * 65536;
        #pragma unroll
        for (int i = 0; i < 4; ++i)
            *(float4*)&D[(long)(r0 + ty * 4 + i) * 256 + j0 + tx * 4] =
                make_float4(acc[i][0], acc[i][1], acc[i][2], acc[i][3]);
    } else if (blk < 136) {
        float* ssx = (float*)smem;
        float* red = ssx + 256;
        const int b = blk - 128, j = t;
        const float sxv = sxpart[b * 256 + j] + sxpart[2048 + b * 256 + j] +
                          sxpart[4096 + b * 256 + j] + sxpart[6144 + b * 256 + j];
        ssx[j] = sxv;
        __syncthreads();
        float vr = 0.0f;
        #pragma unroll 8
        for (int c = 0; c < 256; ++c) vr = fmaf(W3[(long)c * 256 + j], ssx[c], vr); // coalesced
        const float v2j = vr + 2048.0f * u2[j];
        v2[b * 256 + j] = v2j;
        red[j] = v2j * sxv; __syncthreads();
        for (int h = 128; h > 0; h >>= 1) { if (j < h) red[j] += red[j + h]; __syncthreads(); }
        const float sd1 = red[0];
        __syncthreads();
        red[j] = sxv * w1[j]; __syncthreads();
        for (int h = 128; h > 0; h >>= 1) { if (j < h) red[j] += red[j + h]; __syncthreads(); }
        if (j == 0) {
            const float s2v = red[0] + 2048.0f * s1p[0];
            s2[b] = s2v;
            atomicAdd(S, sd1 + 2048.0f * s2v);
        }
    } else {
        float* wtile = (float*)smem;           // 32 x 256
        float* sxs = wtile + 8192;             // 2048
        const int r0w = (blk - 136) * 32;
        #pragma unroll
        for (int p = 0; p < 8; ++p) {
            const int f = t + p * 256;
            const int row = f >> 6, c4 = f & 63;
            *(float4*)&wtile[row * 256 + c4 * 4] = *(const float4*)&Wv[(long)(r0w + row) * 256 + c4 * 4];
        }
        #pragma unroll
        for (int p = 0; p < 2; ++p) {
            const int f = t + p * 256;
            float4 s = make_float4(0.f, 0.f, 0.f, 0.f);
            #pragma unroll
            for (int ks = 0; ks < 4; ++ks) {
                const float4 g = *(const float4*)&sxpart[ks * 2048 + f * 4];
                s.x += g.x; s.y += g.y; s.z += g.z; s.w += g.w;
            }
            *(float4*)&sxs[f * 4] = s;
        }
        __syncthreads();
        const int r = t >> 3, q = t & 7;       // 32 rows x 8 k-groups
        float acc[8] = {};
        for (int ci = 0; ci < 32; ++ci) {
            const float wv = wtile[r * 256 + q * 32 + ci];
            #pragma unroll
            for (int b = 0; b < 8; ++b) acc[b] = fmaf(wv, sxs[b * 256 + q * 32 + ci], acc[b]);
        }
        #pragma unroll
        for (int b = 0; b < 8; ++b) {
            acc[b] += __shfl_xor(acc[b], 1);
            acc[b] += __shfl_xor(acc[b], 2);
            acc[b] += __shfl_xor(acc[b], 4);
        }
        if (q == 0) {
            #pragma unroll
            for (int b = 0; b < 8; ++b) wvsx[b * 256 + r0w + r] = acc[b];
        }
    }
}

// ---------------- K3: Ap = T1 W3 + wvsx(x)u2 + bv(x)v2 -> f16 hi/lo; cvec fold ----------------
__launch_bounds__(256)
__global__ void ap_kernel(const float* __restrict__ T1, const float* __restrict__ W3,
                          const float* __restrict__ wvsx, const float* __restrict__ u2,
                          const float* __restrict__ bv, const float* __restrict__ v2,
                          const float* __restrict__ w1, const float* __restrict__ s1p,
                          const float* __restrict__ s2, _Float16* __restrict__ Aph,
                          _Float16* __restrict__ Apl, float* __restrict__ cvec) {
    __shared__ float ldsA[16 * 68], ldsB[16 * 68], sw1[256];
    const int b = blockIdx.z;
    const int r0 = blockIdx.y * 64, j0 = blockIdx.x * 64;
    const float* A = T1 + (long)b * 65536;
    const int t = threadIdx.x, tx = t & 15, ty = t >> 4;
    const int sr = t >> 2, sk = (t & 3) * 4;
    sw1[t] = w1[t];
    float acc[4][4] = {};
    float dot[4] = {};
    for (int kk = 0; kk < 256; kk += 16) {
        const float4 a4 = *(const float4*)&A[(long)(r0 + sr) * 256 + kk + sk];
        ldsA[(sk + 0) * 68 + sr] = a4.x;
        ldsA[(sk + 1) * 68 + sr] = a4.y;
        ldsA[(sk + 2) * 68 + sr] = a4.z;
        ldsA[(sk + 3) * 68 + sr] = a4.w;
        *(float4*)&ldsB[ty * 68 + tx * 4] = *(const float4*)&W3[(long)(kk + ty) * 256 + j0 + tx * 4];
        __syncthreads();
        #pragma unroll
        for (int k = 0; k < 16; ++k) {
            const float4 av4 = *(const float4*)&ldsA[k * 68 + ty * 4];
            const float4 bv4 = *(const float4*)&ldsB[k * 68 + tx * 4];
            const float ar[4] = {av4.x, av4.y, av4.z, av4.w};
            const float br[4] = {bv4.x, bv4.y, bv4.z, bv4.w};
            const float wk = sw1[kk + k];
            #pragma unroll
            for (int i = 0; i < 4; ++i) {
                dot[i] = fmaf(ar[i], wk, dot[i]);
                #pragma unroll
                for (int j = 0; j < 4; ++j)
                    acc[i][j] = fmaf(ar[i], br[j], acc[i][j]);
            }
        }
        __syncthreads();
    }
    #pragma unroll
    for (int i = 0; i < 4; ++i) {
        const int r = r0 + ty * 4 + i;
        const float e1 = wvsx[b * 256 + r], e3 = bv[r];
        half4 hv, lv;
        #pragma unroll
        for (int j = 0; j < 4; ++j) {
            const int col = j0 + tx * 4 + j;
            const float val = acc[i][j] + e1 * u2[col] + e3 * v2[b * 256 + col];
            hv[j] = (_Float16)val;
            lv[j] = (_Float16)(val - (float)hv[j]);
        }
        const long o = (long)b * 65536 + (long)r * 256 + j0 + tx * 4;
        *(half4*)&Aph[o] = hv;
        *(half4*)&Apl[o] = lv;
        if (j0 == 0 && tx == 0)
            cvec[b * 256 + r] = dot[i] + e1 * s1p[0] + e3 * s2[b];
    }
}

// ---------------- K4: out = (Ap x + cvec 1^T) / S ; x converted in-kernel ----------------
__launch_bounds__(256)
__global__ void gemmF_mfma(const _Float16* __restrict__ Aph, const _Float16* __restrict__ Apl,
                           const float* __restrict__ x, const float* __restrict__ Sptr,
                           const float* __restrict__ cvec, float* __restrict__ out) {
    __shared__ __align__(16) _Float16 Ah[128 * GP];
    __shared__ __align__(16) _Float16 Al[128 * GP];
    __shared__ __align__(16) _Float16 Bh[128 * GPB];
    __shared__ __align__(16) _Float16 Bl[128 * GPB];
    __shared__ __align__(16) float xt[32 * 132];

    const int n0 = blockIdx.x * 128;
    const int c0 = blockIdx.y * 128;
    const int b = blockIdx.z;
    const _Float16* Asrc_h = Aph + (long)b * 65536;
    const _Float16* Asrc_l = Apl + (long)b * 65536;
    const float* xb = x + (long)b * 524288;

    const int t = threadIdx.x;
    const int lane = t & 63, wave = t >> 6;
    const int wy = wave >> 1, wx = wave & 1;
    const int mIn = lane & 15, quad = lane >> 4;

    f4v acc[4][4] = {};
    const int aBase = (wy * 64 + mIn) * GP + quad * 8;
    const int bBase = (wx * 64 + mIn) * GPB + quad * 8;
    const int cn = t & 127;          // converter: n index
    const int ckh = (t >> 7) * 16;   // converter: k half-range

    for (int kk = 0; kk < 256; kk += 32) {
        #pragma unroll
        for (int i = 0; i < 2; ++i) {
            const int idx = t + (i << 8);
            const int row = idx >> 2, ko = (idx & 3) << 3;
            *(uint4*)&Ah[row * GP + ko] = *(const uint4*)&Asrc_h[(long)(c0 + row) * 256 + kk + ko];
            *(uint4*)&Al[row * GP + ko] = *(const uint4*)&Asrc_l[(long)(c0 + row) * 256 + kk + ko];
        }
        #pragma unroll
        for (int p = 0; p < 4; ++p) {
            const int f = t + p * 256;
            const int k = f >> 5, n4 = f & 31;
            *(float4*)&xt[k * 132 + n4 * 4] = *(const float4*)&xb[(long)(kk + k) * 2048 + n0 + n4 * 4];
        }
        __syncthreads();
        {
            _Float16 hs[16], ls[16];
            #pragma unroll
            for (int k = 0; k < 16; ++k) {
                const float v = xt[(ckh + k) * 132 + cn];      // 2-way LDS read (free)
                hs[k] = (_Float16)v;
                ls[k] = (_Float16)(v - (float)hs[k]);
            }
            #pragma unroll
            for (int k2 = 0; k2 < 8; ++k2) {
                half2v h2; h2[0] = hs[2 * k2]; h2[1] = hs[2 * k2 + 1];
                half2v l2; l2[0] = ls[2 * k2]; l2[1] = ls[2 * k2 + 1];
                *(half2v*)&Bh[cn * GPB + ckh + 2 * k2] = h2;   // 18-dword stride: 2-way (free)
                *(half2v*)&Bl[cn * GPB + ckh + 2 * k2] = l2;
            }
        }
        __syncthreads();
        #pragma unroll
        for (int ph = 0; ph < 3; ++ph) {
            const _Float16* As = (ph == 2) ? Al : Ah;
            const _Float16* Bs = (ph == 1) ? Bl : Bh;
            half8 af[4], bf[4];
            #pragma unroll
            for (int i = 0; i < 4; ++i) {
                af[i] = *(const half8*)&As[aBase + i * 16 * GP];
                const half4 b0 = *(const half4*)&Bs[bBase + i * 16 * GPB];
                const half4 b1 = *(const half4*)&Bs[bBase + i * 16 * GPB + 4];
                bf[i] = __builtin_shufflevector(b0, b1, 0, 1, 2, 3, 4, 5, 6, 7);
            }
            #pragma unroll
            for (int i = 0; i < 4; ++i)
                #pragma unroll
                for (int j = 0; j < 4; ++j)
                    acc[i][j] = __builtin_amdgcn_mfma_f32_16x16x32_f16(af[i], bf[j], acc[i][j], 0, 0, 0);
        }
        __syncthreads();
    }

    const float invS = 1.0f / Sptr[0];
    float* ob = out + (long)b * 524288;
    const float* cv = cvec + b * 256;
    #pragma unroll
    for (int i = 0; i < 4; ++i)
        #pragma unroll
        for (int r = 0; r < 4; ++r) {
            const int row = c0 + wy * 64 + i * 16 + quad * 4 + r;
            const float c = cv[row];
            #pragma unroll
            for (int j = 0; j < 4; ++j) {
                const int col = n0 + wx * 64 + j * 16 + mIn;
                ob[(long)row * 2048 + col] = (acc[i][j][r] + c) * invS;
            }
        }
}

extern "C" void kernel_launch(void* const* d_in, const int* in_sizes, int n_in,
                              void* d_out, int out_size, void* d_ws, size_t ws_size,
                              hipStream_t stream) {
    const float* x  = (const float*)d_in[0];
    const float* Wq = (const float*)d_in[1];
    const float* bq = (const float*)d_in[2];
    const float* Wk = (const float*)d_in[3];
    const float* bk = (const float*)d_in[4];
    const float* Wv = (const float*)d_in[5];
    const float* bv = (const float*)d_in[6];
    float* out = (float*)d_out;
    float* ws  = (float*)d_ws;

    float* T1     = ws;                  // 524288
    float* W3     = ws + 524288;         // 65536
    float* sxpart = ws + 589824;         // 4*2048
    float* wvsx   = ws + 598016;         // 2048
    float* v2     = ws + 600064;         // 2048
    float* cvec   = ws + 602112;         // 2048
    float* s2     = ws + 604160;         // 8
    float* u2     = ws + 604168;         // 256
    float* w1     = ws + 604424;         // 256
    float* s1     = ws + 604680;         // 1
    float* S      = ws + 604681;         // 1
    float* Gpart  = ws + 604688;         // 4*8*65536 = 2097152 (8 MB)
    _Float16* Aph = (_Float16*)(ws + 2701840);   // 524288 halves
    _Float16* Apl = Aph + 524288;                // total ws ~12.9 MB

    k1_kernel<<<dim3(113), 256, 0, stream>>>(x, Wq, Wk, bq, bk, sxpart, W3, u2, w1, s1, S, Gpart);
    k2_kernel<<<dim3(144), 256, 0, stream>>>(Wv, Gpart, W3, u2, w1, s1, sxpart, T1, v2, s2, wvsx, S);
    ap_kernel<<<dim3(4, 4, 8), 256, 0, stream>>>(T1, W3, wvsx, u2, bv, v2, w1, s1, s2, Aph, Apl, cvec);
    gemmF_mfma<<<dim3(16, 2, 8), 256, 0, stream>>>(Aph, Apl, x, S, cvec, out);
}

// Round 9
// 151.893 us; speedup vs baseline: 1.9077x; 1.0235x over previous
//
#include <hip/hip_runtime.h>

// B=8, C=256, N=2048, fp32 in/out.
// attn_b = (Ap_b x_b + cvec_b 1^T) / S
//   Ap_b = T1_b W3 + wvsx_b (x) u2 + bv (x) v2_b      (f16 hi/lo split MFMA)
//   T1_b = Wv G_b,  W3 = Wq^T Wk,  G_b = x_b x_b^T (symmetric)
//   u2 = Wk^T bq, w1 = Wq^T bk, s1 = bq.bk, sx_b = rowsum(x_b)
//   v2_b = W3^T sx_b + N u2;  s2_b = sx.w1 + N s1;  S = sum_b [v2.sx + N s2]
//   cvec_b = T1.w1 + wvsx*s1 + bv*s2    (computed inside ap)
// 4 serial nodes (round-7 structure; cooperative mega-kernel FAILED in harness):
//   K1(gemmG splitK=8 + rowsum || W3 || u2w1s1) -> K2(t1 || prep2 || wvsx)
//   -> K3(ap + cvec) -> K4(gemmF, in-kernel x transpose-convert)

typedef _Float16 half8 __attribute__((ext_vector_type(8)));
typedef _Float16 half4 __attribute__((ext_vector_type(4)));
typedef _Float16 half2v __attribute__((ext_vector_type(2)));
typedef float f4v __attribute__((ext_vector_type(4)));

#define GP  40   // LDS pitch (halves), A panels / gemmG (16B-aligned rows)
#define GPB 36   // gemmF B panel pitch: 18-dword row stride -> 2-way (free) banking

// ---------------- K1: gemmG splitK=8 (+rowsum) | W3 | u2/w1/s1 ----------------
// blocks 0..191: gemmG; 192..207: W3 tiles; 208: u2/w1/s1 + zero S.
__launch_bounds__(256)
__global__ void k1_kernel(const float* __restrict__ x, const float* __restrict__ Wq,
                          const float* __restrict__ Wk, const float* __restrict__ bq,
                          const float* __restrict__ bk, float* __restrict__ sxpart,
                          float* __restrict__ W3, float* __restrict__ u2,
                          float* __restrict__ w1, float* __restrict__ s1,
                          float* __restrict__ S, float* __restrict__ Gpart) {
    __shared__ __align__(16) char smem[40960];
    const int blk = blockIdx.x, t = threadIdx.x;
    if (blk < 192) {
        _Float16* Ah = (_Float16*)smem;
        _Float16* Al = Ah + 128 * GP;
        _Float16* Bh = Al + 128 * GP;
        _Float16* Bl = Bh + 128 * GP;
        const int tileId = blk % 3;
        const int y = blk / 3;                 // 0..63
        const int b = y >> 3, ks = y & 7;
        const int r0 = (tileId == 2) ? 128 : 0;
        const int c0 = (tileId == 0) ? 0 : 128;
        const bool diag = (tileId != 1);
        const float* xb = x + (long)b * 524288;

        const int lane = t & 63, wave = t >> 6;
        const int wy = wave >> 1, wx = wave & 1;
        const int mIn = lane & 15, quad = lane >> 4;

        f4v acc[4][4] = {};
        const int aBase = (wy * 64 + mIn) * GP + quad * 8;
        const int bBase = (wx * 64 + mIn) * GP + quad * 8;
        const int srow = t >> 3;               // 0..31
        const int skq  = (t & 7) * 4;          // 0..28
        float rs[4] = {};                      // rowsum partials (diag only)

        float4 pa[4], pb[4];
        int kk = ks * 256;
        #pragma unroll
        for (int i = 0; i < 4; ++i) {
            pa[i] = *(const float4*)&xb[(long)(r0 + srow + i * 32) * 2048 + kk + skq];
            if (!diag) pb[i] = *(const float4*)&xb[(long)(c0 + srow + i * 32) * 2048 + kk + skq];
        }

        for (int kb = 0; kb < 8; ++kb) {
            if (kb) __syncthreads();
            #pragma unroll
            for (int i = 0; i < 4; ++i) {
                const int row = srow + i * 32;
                half4 hv, lv;
                hv[0] = (_Float16)pa[i].x; lv[0] = (_Float16)(pa[i].x - (float)hv[0]);
                hv[1] = (_Float16)pa[i].y; lv[1] = (_Float16)(pa[i].y - (float)hv[1]);
                hv[2] = (_Float16)pa[i].z; lv[2] = (_Float16)(pa[i].z - (float)hv[2]);
                hv[3] = (_Float16)pa[i].w; lv[3] = (_Float16)(pa[i].w - (float)hv[3]);
                *(half4*)&Ah[row * GP + skq] = hv;
                *(half4*)&Al[row * GP + skq] = lv;
                if (diag) {
                    rs[i] += pa[i].x + pa[i].y + pa[i].z + pa[i].w;
                } else {
                    half4 hb, lb;
                    hb[0] = (_Float16)pb[i].x; lb[0] = (_Float16)(pb[i].x - (float)hb[0]);
                    hb[1] = (_Float16)pb[i].y; lb[1] = (_Float16)(pb[i].y - (float)hb[1]);
                    hb[2] = (_Float16)pb[i].z; lb[2] = (_Float16)(pb[i].z - (float)hb[2]);
                    hb[3] = (_Float16)pb[i].w; lb[3] = (_Float16)(pb[i].w - (float)hb[3]);
                    *(half4*)&Bh[row * GP + skq] = hb;
                    *(half4*)&Bl[row * GP + skq] = lb;
                }
            }
            __syncthreads();
            kk += 32;
            if (kb < 7) {
                #pragma unroll
                for (int i = 0; i < 4; ++i) {
                    pa[i] = *(const float4*)&xb[(long)(r0 + srow + i * 32) * 2048 + kk + skq];
                    if (!diag) pb[i] = *(const float4*)&xb[(long)(c0 + srow + i * 32) * 2048 + kk + skq];
                }
            }
            const _Float16* BhP = diag ? Ah : Bh;
            const _Float16* BlP = diag ? Al : Bl;
            #pragma unroll
            for (int ph = 0; ph < 3; ++ph) {
                const _Float16* As = (ph == 2) ? Al : Ah;
                const _Float16* Bs = (ph == 1) ? BlP : BhP;
                half8 af[4], bf[4];
                #pragma unroll
                for (int i = 0; i < 4; ++i) {
                    af[i] = *(const half8*)&As[aBase + i * 16 * GP];
                    bf[i] = *(const half8*)&Bs[bBase + i * 16 * GP];
                }
                #pragma unroll
                for (int i = 0; i < 4; ++i)
                    #pragma unroll
                    for (int j = 0; j < 4; ++j)
                        acc[i][j] = __builtin_amdgcn_mfma_f32_16x16x32_f16(af[i], bf[j], acc[i][j], 0, 0, 0);
            }
        }

        if (diag) {
            #pragma unroll
            for (int i = 0; i < 4; ++i) {
                rs[i] += __shfl_xor(rs[i], 1);
                rs[i] += __shfl_xor(rs[i], 2);
                rs[i] += __shfl_xor(rs[i], 4);
            }
            if ((t & 7) == 0) {
                #pragma unroll
                for (int i = 0; i < 4; ++i)
                    sxpart[ks * 2048 + b * 256 + r0 + srow + i * 32] = rs[i];
            }
        }

        float* D = Gpart + ((long)(ks * 8 + b) << 16);
        #pragma unroll
        for (int i = 0; i < 4; ++i)
            #pragma unroll
            for (int j = 0; j < 4; ++j) {
                const int row = r0 + wy * 64 + i * 16 + quad * 4;
                const int col = c0 + wx * 64 + j * 16 + mIn;
                #pragma unroll
                for (int r = 0; r < 4; ++r)
                    D[(row + r) * 256 + col] = acc[i][j][r];
                if (tileId == 1)
                    *(float4*)&D[(long)col * 256 + row] =
                        make_float4(acc[i][j][0], acc[i][j][1], acc[i][j][2], acc[i][j][3]);
            }
    } else if (blk < 208) {
        float* ldsA = (float*)smem;
        float* ldsB = ldsA + 16 * 68;
        const int tile = blk - 192;
        const int r0 = (tile >> 2) * 64, j0 = (tile & 3) * 64;
        const int tx = t & 15, ty = t >> 4;
        float acc[4][4] = {};
        for (int kk = 0; kk < 256; kk += 16) {
            *(float4*)&ldsA[ty * 68 + tx * 4] = *(const float4*)&Wq[(long)(kk + ty) * 256 + r0 + tx * 4];
            *(float4*)&ldsB[ty * 68 + tx * 4] = *(const float4*)&Wk[(long)(kk + ty) * 256 + j0 + tx * 4];
            __syncthreads();
            #pragma unroll
            for (int k = 0; k < 16; ++k) {
                const float4 av4 = *(const float4*)&ldsA[k * 68 + ty * 4];
                const float4 bv4 = *(const float4*)&ldsB[k * 68 + tx * 4];
                const float ar[4] = {av4.x, av4.y, av4.z, av4.w};
                const float br[4] = {bv4.x, bv4.y, bv4.z, bv4.w};
                #pragma unroll
                for (int i = 0; i < 4; ++i)
                    #pragma unroll
                    for (int j = 0; j < 4; ++j)
                        acc[i][j] = fmaf(ar[i], br[j], acc[i][j]);
            }
            __syncthreads();
        }
        #pragma unroll
        for (int i = 0; i < 4; ++i)
            *(float4*)&W3[(long)(r0 + ty * 4 + i) * 256 + j0 + tx * 4] =
                make_float4(acc[i][0], acc[i][1], acc[i][2], acc[i][3]);
    } else {
        float* sbq = (float*)smem;
        float* sbk = sbq + 256;
        float* red = sbk + 256;
        if (t == 0) S[0] = 0.0f;
        sbq[t] = bq[t]; sbk[t] = bk[t];
        __syncthreads();
        float u = 0.0f, w = 0.0f;
        #pragma unroll 8
        for (int c = 0; c < 256; ++c) {
            u = fmaf(Wk[(long)c * 256 + t], sbq[c], u);   // coalesced columns
            w = fmaf(Wq[(long)c * 256 + t], sbk[c], w);
        }
        u2[t] = u; w1[t] = w;
        red[t] = sbq[t] * sbk[t]; __syncthreads();
        for (int h = 128; h > 0; h >>= 1) { if (t < h) red[t] += red[t + h]; __syncthreads(); }
        if (t == 0) s1[0] = red[0];
    }
}

// ---------------- K2: t1 (0..127) | prep2 (128..135) | wvsx (136..143) ----------------
__launch_bounds__(256)
__global__ void k2_kernel(const float* __restrict__ Wv, const float* __restrict__ Gpart,
                          const float* __restrict__ W3, const float* __restrict__ u2,
                          const float* __restrict__ w1, const float* __restrict__ s1p,
                          const float* __restrict__ sxpart, float* __restrict__ T1,
                          float* __restrict__ v2, float* __restrict__ s2,
                          float* __restrict__ wvsx, float* __restrict__ S) {
    __shared__ __align__(16) char smem[40960];
    const int blk = blockIdx.x, t = threadIdx.x;
    if (blk < 128) {
        float* ldsA = (float*)smem;
        float* ldsB = ldsA + 16 * 68;
        const int j0 = (blk & 3) * 64;
        const int r0 = ((blk >> 2) & 3) * 64;
        const int b = blk >> 4;
        const int tx = t & 15, ty = t >> 4;
        const int sr = t >> 2, sk = (t & 3) * 4;
        float acc[4][4] = {};
        for (int kk = 0; kk < 256; kk += 16) {
            const float4 a4 = *(const float4*)&Wv[(long)(r0 + sr) * 256 + kk + sk];
            ldsA[(sk + 0) * 68 + sr] = a4.x;
            ldsA[(sk + 1) * 68 + sr] = a4.y;
            ldsA[(sk + 2) * 68 + sr] = a4.z;
            ldsA[(sk + 3) * 68 + sr] = a4.w;
            float4 bs = make_float4(0.f, 0.f, 0.f, 0.f);
            #pragma unroll
            for (int ksl = 0; ksl < 8; ++ksl) {         // fold splitK reduce into staging
                const float4 g = *(const float4*)&Gpart[(long)ksl * 524288 + (long)b * 65536 +
                                                        (long)(kk + ty) * 256 + j0 + tx * 4];
                bs.x += g.x; bs.y += g.y; bs.z += g.z; bs.w += g.w;
            }
            *(float4*)&ldsB[ty * 68 + tx * 4] = bs;
            __syncthreads();
            #pragma unroll
            for (int k = 0; k < 16; ++k) {
                const float4 av4 = *(const float4*)&ldsA[k * 68 + ty * 4];
                const float4 bv4 = *(const float4*)&ldsB[k * 68 + tx * 4];
                const float ar[4] = {av4.x, av4.y, av4.z, av4.w};
                const float br[4] = {bv4.x, bv4.y, bv4.z, bv4.w};
                #pragma unroll
                for (int i = 0; i < 4; ++i)
                    #pragma unroll
                    for (int j = 0; j < 4; ++j)
                        acc[i][j] = fmaf(ar[i], br[j], acc[i][j]);
            }
            __syncthreads();
        }
        float* D = T1 + (long)b * 65536;
        #pragma unroll
        for (int i = 0; i < 4; ++i)
            *(float4*)&D[(long)(r0 + ty * 4 + i) * 256 + j0 + tx * 4] =
                make_float4(acc[i][0], acc[i][1], acc[i][2], acc[i][3]);
    } else if (blk < 136) {
        float* ssx = (float*)smem;
        float* red = ssx + 256;
        const int b = blk - 128, j = t;
        float sxv = 0.0f;
        #pragma unroll
        for (int ks = 0; ks < 8; ++ks) sxv += sxpart[ks * 2048 + b * 256 + j];
        ssx[j] = sxv;
        __syncthreads();
        float vr = 0.0f;
        #pragma unroll 8
        for (int c = 0; c < 256; ++c) vr = fmaf(W3[(long)c * 256 + j], ssx[c], vr); // coalesced
        const float v2j = vr + 2048.0f * u2[j];
        v2[b * 256 + j] = v2j;
        red[j] = v2j * sxv; __syncthreads();
        for (int h = 128; h > 0; h >>= 1) { if (j < h) red[j] += red[j + h]; __syncthreads(); }
        const float sd1 = red[0];
        __syncthreads();
        red[j] = sxv * w1[j]; __syncthreads();
        for (int h = 128; h > 0; h >>= 1) { if (j < h) red[j] += red[j + h]; __syncthreads(); }
        if (j == 0) {
            const float s2v = red[0] + 2048.0f * s1p[0];
            s2[b] = s2v;
            atomicAdd(S, sd1 + 2048.0f * s2v);
        }
    } else {
        float* wtile = (float*)smem;           // 32 x 256
        float* sxs = wtile + 8192;             // 2048
        const int r0w = (blk - 136) * 32;
        #pragma unroll
        for (int p = 0; p < 8; ++p) {
            const int f = t + p * 256;
            const int row = f >> 6, c4 = f & 63;
            *(float4*)&wtile[row * 256 + c4 * 4] = *(const float4*)&Wv[(long)(r0w + row) * 256 + c4 * 4];
        }
        #pragma unroll
        for (int p = 0; p < 8; ++p) {
            const int f = t + p * 256;
            float s = 0.0f;
            #pragma unroll
            for (int ks = 0; ks < 8; ++ks) s += sxpart[ks * 2048 + f];
            sxs[f] = s;
        }
        __syncthreads();
        const int r = t >> 3, q = t & 7;       // 32 rows x 8 k-groups
        float acc[8] = {};
        for (int ci = 0; ci < 32; ++ci) {
            const float wv = wtile[r * 256 + q * 32 + ci];
            #pragma unroll
            for (int b = 0; b < 8; ++b) acc[b] = fmaf(wv, sxs[b * 256 + q * 32 + ci], acc[b]);
        }
        #pragma unroll
        for (int b = 0; b < 8; ++b) {
            acc[b] += __shfl_xor(acc[b], 1);
            acc[b] += __shfl_xor(acc[b], 2);
            acc[b] += __shfl_xor(acc[b], 4);
        }
        if (q == 0) {
            #pragma unroll
            for (int b = 0; b < 8; ++b) wvsx[b * 256 + r0w + r] = acc[b];
        }
    }
}

// ---------------- K3: Ap = T1 W3 + wvsx(x)u2 + bv(x)v2 -> f16 hi/lo; cvec fold ----------------
__launch_bounds__(256)
__global__ void ap_kernel(const float* __restrict__ T1, const float* __restrict__ W3,
                          const float* __restrict__ wvsx, const float* __restrict__ u2,
                          const float* __restrict__ bv, const float* __restrict__ v2,
                          const float* __restrict__ w1, const float* __restrict__ s1p,
                          const float* __restrict__ s2, _Float16* __restrict__ Aph,
                          _Float16* __restrict__ Apl, float* __restrict__ cvec) {
    __shared__ float ldsA[16 * 68], ldsB[16 * 68], sw1[256];
    const int b = blockIdx.z;
    const int r0 = blockIdx.y * 64, j0 = blockIdx.x * 64;
    const float* A = T1 + (long)b * 65536;
    const int t = threadIdx.x, tx = t & 15, ty = t >> 4;
    const int sr = t >> 2, sk = (t & 3) * 4;
    sw1[t] = w1[t];
    float acc[4][4] = {};
    float dot[4] = {};
    for (int kk = 0; kk < 256; kk += 16) {
        const float4 a4 = *(const float4*)&A[(long)(r0 + sr) * 256 + kk + sk];
        ldsA[(sk + 0) * 68 + sr] = a4.x;
        ldsA[(sk + 1) * 68 + sr] = a4.y;
        ldsA[(sk + 2) * 68 + sr] = a4.z;
        ldsA[(sk + 3) * 68 + sr] = a4.w;
        *(float4*)&ldsB[ty * 68 + tx * 4] = *(const float4*)&W3[(long)(kk + ty) * 256 + j0 + tx * 4];
        __syncthreads();
        #pragma unroll
        for (int k = 0; k < 16; ++k) {
            const float4 av4 = *(const float4*)&ldsA[k * 68 + ty * 4];
            const float4 bv4 = *(const float4*)&ldsB[k * 68 + tx * 4];
            const float ar[4] = {av4.x, av4.y, av4.z, av4.w};
            const float br[4] = {bv4.x, bv4.y, bv4.z, bv4.w};
            const float wk = sw1[kk + k];
            #pragma unroll
            for (int i = 0; i < 4; ++i) {
                dot[i] = fmaf(ar[i], wk, dot[i]);
                #pragma unroll
                for (int j = 0; j < 4; ++j)
                    acc[i][j] = fmaf(ar[i], br[j], acc[i][j]);
            }
        }
        __syncthreads();
    }
    #pragma unroll
    for (int i = 0; i < 4; ++i) {
        const int r = r0 + ty * 4 + i;
        const float e1 = wvsx[b * 256 + r], e3 = bv[r];
        half4 hv, lv;
        #pragma unroll
        for (int j = 0; j < 4; ++j) {
            const int col = j0 + tx * 4 + j;
            const float val = acc[i][j] + e1 * u2[col] + e3 * v2[b * 256 + col];
            hv[j] = (_Float16)val;
            lv[j] = (_Float16)(val - (float)hv[j]);
        }
        const long o = (long)b * 65536 + (long)r * 256 + j0 + tx * 4;
        *(half4*)&Aph[o] = hv;
        *(half4*)&Apl[o] = lv;
        if (j0 == 0 && tx == 0)
            cvec[b * 256 + r] = dot[i] + e1 * s1p[0] + e3 * s2[b];
    }
}

// ---------------- K4: out = (Ap x + cvec 1^T) / S ; x converted in-kernel ----------------
__launch_bounds__(256)
__global__ void gemmF_mfma(const _Float16* __restrict__ Aph, const _Float16* __restrict__ Apl,
                           const float* __restrict__ x, const float* __restrict__ Sptr,
                           const float* __restrict__ cvec, float* __restrict__ out) {
    __shared__ __align__(16) _Float16 Ah[128 * GP];
    __shared__ __align__(16) _Float16 Al[128 * GP];
    __shared__ __align__(16) _Float16 Bh[128 * GPB];
    __shared__ __align__(16) _Float16 Bl[128 * GPB];
    __shared__ __align__(16) float xt[32 * 132];

    const int n0 = blockIdx.x * 128;
    const int c0 = blockIdx.y * 128;
    const int b = blockIdx.z;
    const _Float16* Asrc_h = Aph + (long)b * 65536;
    const _Float16* Asrc_l = Apl + (long)b * 65536;
    const float* xb = x + (long)b * 524288;

    const int t = threadIdx.x;
    const int lane = t & 63, wave = t >> 6;
    const int wy = wave >> 1, wx = wave & 1;
    const int mIn = lane & 15, quad = lane >> 4;

    f4v acc[4][4] = {};
    const int aBase = (wy * 64 + mIn) * GP + quad * 8;
    const int bBase = (wx * 64 + mIn) * GPB + quad * 8;
    const int cn = t & 127;          // converter: n index
    const int ckh = (t >> 7) * 16;   // converter: k half-range

    for (int kk = 0; kk < 256; kk += 32) {
        #pragma unroll
        for (int i = 0; i < 2; ++i) {
            const int idx = t + (i << 8);
            const int row = idx >> 2, ko = (idx & 3) << 3;
            *(uint4*)&Ah[row * GP + ko] = *(const uint4*)&Asrc_h[(long)(c0 + row) * 256 + kk + ko];
            *(uint4*)&Al[row * GP + ko] = *(const uint4*)&Asrc_l[(long)(c0 + row) * 256 + kk + ko];
        }
        #pragma unroll
        for (int p = 0; p < 4; ++p) {
            const int f = t + p * 256;
            const int k = f >> 5, n4 = f & 31;
            *(float4*)&xt[k * 132 + n4 * 4] = *(const float4*)&xb[(long)(kk + k) * 2048 + n0 + n4 * 4];
        }
        __syncthreads();
        {
            _Float16 hs[16], ls[16];
            #pragma unroll
            for (int k = 0; k < 16; ++k) {
                const float v = xt[(ckh + k) * 132 + cn];      // 2-way LDS read (free)
                hs[k] = (_Float16)v;
                ls[k] = (_Float16)(v - (float)hs[k]);
            }
            #pragma unroll
            for (int k2 = 0; k2 < 8; ++k2) {
                half2v h2; h2[0] = hs[2 * k2]; h2[1] = hs[2 * k2 + 1];
                half2v l2; l2[0] = ls[2 * k2]; l2[1] = ls[2 * k2 + 1];
                *(half2v*)&Bh[cn * GPB + ckh + 2 * k2] = h2;   // 18-dword stride: 2-way (free)
                *(half2v*)&Bl[cn * GPB + ckh + 2 * k2] = l2;
            }
        }
        __syncthreads();
        #pragma unroll
        for (int ph = 0; ph < 3; ++ph) {
            const _Float16* As = (ph == 2) ? Al : Ah;
            const _Float16* Bs = (ph == 1) ? Bl : Bh;
            half8 af[4], bf[4];
            #pragma unroll
            for (int i = 0; i < 4; ++i) {
                af[i] = *(const half8*)&As[aBase + i * 16 * GP];
                const half4 b0 = *(const half4*)&Bs[bBase + i * 16 * GPB];
                const half4 b1 = *(const half4*)&Bs[bBase + i * 16 * GPB + 4];
                bf[i] = __builtin_shufflevector(b0, b1, 0, 1, 2, 3, 4, 5, 6, 7);
            }
            #pragma unroll
            for (int i = 0; i < 4; ++i)
                #pragma unroll
                for (int j = 0; j < 4; ++j)
                    acc[i][j] = __builtin_amdgcn_mfma_f32_16x16x32_f16(af[i], bf[j], acc[i][j], 0, 0, 0);
        }
        __syncthreads();
    }

    const float invS = 1.0f / Sptr[0];
    float* ob = out + (long)b * 524288;
    const float* cv = cvec + b * 256;
    #pragma unroll
    for (int i = 0; i < 4; ++i)
        #pragma unroll
        for (int r = 0; r < 4; ++r) {
            const int row = c0 + wy * 64 + i * 16 + quad * 4 + r;
            const float c = cv[row];
            #pragma unroll
            for (int j = 0; j < 4; ++j) {
                const int col = n0 + wx * 64 + j * 16 + mIn;
                ob[(long)row * 2048 + col] = (acc[i][j][r] + c) * invS;
            }
        }
}

extern "C" void kernel_launch(void* const* d_in, const int* in_sizes, int n_in,
                              void* d_out, int out_size, void* d_ws, size_t ws_size,
                              hipStream_t stream) {
    const float* x  = (const float*)d_in[0];
    const float* Wq = (const float*)d_in[1];
    const float* bq = (const float*)d_in[2];
    const float* Wk = (const float*)d_in[3];
    const float* bk = (const float*)d_in[4];
    const float* Wv = (const float*)d_in[5];
    const float* bv = (const float*)d_in[6];
    float* out = (float*)d_out;
    float* ws  = (float*)d_ws;

    float* T1     = ws;                  // 524288
    float* W3     = ws + 524288;         // 65536
    float* sxpart = ws + 589824;         // 8*2048
    float* wvsx   = ws + 606208;         // 2048
    float* v2     = ws + 608256;         // 2048
    float* cvec   = ws + 610304;         // 2048
    float* s2     = ws + 612352;         // 8
    float* u2     = ws + 612360;         // 256
    float* w1     = ws + 612616;         // 256
    float* s1     = ws + 612872;         // 1
    float* S      = ws + 612873;         // 1
    float* Gpart  = ws + 612880;         // 8*8*65536 = 4194304 (16 MB)
    _Float16* Aph = (_Float16*)(ws + 4807184);   // 524288 halves
    _Float16* Apl = Aph + 524288;                // total ws ~21 MB

    k1_kernel<<<dim3(209), 256, 0, stream>>>(x, Wq, Wk, bq, bk, sxpart, W3, u2, w1, s1, S, Gpart);
    k2_kernel<<<dim3(144), 256, 0, stream>>>(Wv, Gpart, W3, u2, w1, s1, sxpart, T1, v2, s2, wvsx, S);
    ap_kernel<<<dim3(4, 4, 8), 256, 0, stream>>>(T1, W3, wvsx, u2, bv, v2, w1, s1, s2, Aph, Apl, cvec);
    gemmF_mfma<<<dim3(16, 2, 8), 256, 0, stream>>>(Aph, Apl, x, S, cvec, out);
}